// Round 8
// baseline (245.510 us; speedup 1.0000x reference)
//
#include <hip/hip_runtime.h>
#include <hip/hip_bf16.h>
#include <math.h>
#include <stddef.h>

#define DEV __device__ __forceinline__
__device__ const float BNS = 0.99999500003749968f; // 1/sqrt(1+1e-5)

typedef __bf16 bf16x8 __attribute__((ext_vector_type(8)));
typedef float  f32x4  __attribute__((ext_vector_type(4)));

#define MF(a,b,c) __builtin_amdgcn_mfma_f32_16x16x32_bf16(a,b,c,0,0,0)

DEV unsigned short f2bs(float v){
  union{ __hip_bfloat16 b; unsigned short u; } c; c.b=__float2bfloat16(v); return c.u;
}
DEV float bs2f(unsigned short u){
  union{ unsigned short u; __hip_bfloat16 b; } c; c.u=u; return __bfloat162float(c.b);
}

// Chunked split-bf16 LDS layout: chunk cc covers channels [cc*32, cc*32+32),
// 64 rows x 64 ushorts (32 hi + 32 lo), XOR-swizzled like the GEMM staging:
// unit up = u ^ (row&7), u<4 = hi k-offset u*8, u>=4 = lo.
// Channel quads c0..c0+3 (c0 % 4 == 0) are CONTIGUOUS ushorts -> vector ops.
DEV void put_split4(unsigned short* chunks, int n, int c0, const float* v){
  int cc=c0>>5, u=(c0>>3)&3, e=c0&7;          // e in {0,4}
  unsigned short* base = chunks + cc*4096;
  unsigned short h0=f2bs(v[0]), h1=f2bs(v[1]), h2=f2bs(v[2]), h3=f2bs(v[3]);
  ushort4 hq = make_ushort4(h0,h1,h2,h3);
  ushort4 lq = make_ushort4(f2bs(v[0]-bs2f(h0)), f2bs(v[1]-bs2f(h1)),
                            f2bs(v[2]-bs2f(h2)), f2bs(v[3]-bs2f(h3)));
  *(ushort4*)&base[(n*8 + (u     ^ (n&7)))*8 + e] = hq;
  *(ushort4*)&base[(n*8 + ((u+4) ^ (n&7)))*8 + e] = lq;
}
DEV void get_split4(const unsigned short* chunks, int n, int c0, float* v){
  int cc=c0>>5, u=(c0>>3)&3, e=c0&7;
  const unsigned short* base = chunks + cc*4096;
  ushort4 hq = *(const ushort4*)&base[(n*8 + (u     ^ (n&7)))*8 + e];
  ushort4 lq = *(const ushort4*)&base[(n*8 + ((u+4) ^ (n&7)))*8 + e];
  v[0]=bs2f(hq.x)+bs2f(lq.x); v[1]=bs2f(hq.y)+bs2f(lq.y);
  v[2]=bs2f(hq.z)+bs2f(lq.z); v[3]=bs2f(hq.w)+bs2f(lq.w);
}

// Geometry: B=2, M=256 -> 512 bm groups, N=64 pts, KNN=16, CIN=64,
// edge1 O=64, edge2 O=128, SUMM=192, CALIB=64, EXP=256/512, OUT=256. f32 I/O.
// Split-bf16 activation layout in cats: [row][2][192] ushort (hi, lo).

// ------- fused prep: 6 weight splits + 3 head transposes in one launch ------
__global__ __launch_bounds__(256) void k_prep(const float* __restrict__ e1_w,
    const float* __restrict__ e2_w, const float* __restrict__ cal1_w,
    const float* __restrict__ cal2_w, const float* __restrict__ exp1_w,
    const float* __restrict__ exp2_w, unsigned short* __restrict__ Whi,
    unsigned short* __restrict__ Wlo,
    const float* __restrict__ red_w, const float* __restrict__ sc1_w,
    const float* __restrict__ sc2_w, float* __restrict__ Wt_red,
    float* __restrict__ Wt_s1, float* __restrict__ Wt_s2){
  __shared__ float s[32][33];
  int bid = blockIdx.x;
  if(bid < 896){
    const float* src; unsigned short *hi,*lo; int mode, O=0, i0;
    if(bid<32)      { src=e1_w;  hi=Whi;       lo=Wlo;       mode=1; O= 64; i0=bid*256; }
    else if(bid<96) { src=e2_w;  hi=Whi+8192;  lo=Wlo+8192;  mode=1; O=128; i0=(bid-32)*256; }
    else if(bid<144){ src=cal1_w;hi=Whi+24576; lo=Wlo+24576; mode=0;        i0=(bid-96)*256; }
    else if(bid<192){ src=cal2_w;hi=Whi+36864; lo=Wlo+36864; mode=0;        i0=(bid-144)*256; }
    else if(bid<384){ src=exp1_w;hi=Whi+49152; lo=Wlo+49152; mode=0;        i0=(bid-192)*256; }
    else            { src=exp2_w;hi=Whi+98304; lo=Wlo+98304; mode=0;        i0=(bid-384)*256; }
    int i = i0 + threadIdx.x;
    float v;
    if(mode==0) v = src[i];
    else { // edge rows: [W1 ; W2-W1] over [2O][64]
      int row=i>>6, c=i&63;
      v = (row<O) ? src[row*128+c] : (src[(row-O)*128+64+c]-src[(row-O)*128+c]);
    }
    unsigned short h=f2bs(v); hi[i]=h; lo[i]=f2bs(v-bs2f(h));
  } else {
    int lb = bid-896;
    const float* in; float* out; int O,K;
    if(lb<128){ in=red_w; out=Wt_red; O=256; K=512; }
    else if(lb<192){ in=sc1_w; out=Wt_s1; O=256; K=256; lb-=128; }
    else { in=sc2_w; out=Wt_s2; O=256; K=256; lb-=192; }
    int nt=O>>5;
    int to=lb%nt, tk=lb/nt;
    int c=threadIdx.x&31, r8=threadIdx.x>>5;
    #pragma unroll
    for(int p=0;p<4;p++){
      int r=r8+p*8;
      s[r][c]=in[(size_t)(to*32+r)*K + tk*32 + c];
    }
    __syncthreads();
    #pragma unroll
    for(int p=0;p<4;p++){
      int r=r8+p*8;
      out[(size_t)(tk*32+r)*O + to*32 + c]=s[c][r];
    }
  }
}

// -------- fused knn + edge1 + edge2: per bm, all in LDS ---------------------
// 512 threads / 8 waves; 56 KB LDS -> 2 blocks/CU.
// zs/ds buffers TRANSPOSED to [point][channel] (stride 68, 16B-aligned rows):
// MFMA epilogue = f32x4 stores; neighbor gather = float4 reads along channels
// (4x fewer LDS instrs than the scalar [ch][pt] gather).
__global__ __launch_bounds__(512) void k_knne12(const float* __restrict__ xyz,
    const float* __restrict__ feats,
    const unsigned short* __restrict__ W1h, const unsigned short* __restrict__ W1l,
    const unsigned short* __restrict__ W2h, const unsigned short* __restrict__ W2l,
    const float* __restrict__ g1, const float* __restrict__ b1,
    const float* __restrict__ g2, const float* __restrict__ b2,
    unsigned short* __restrict__ cat){
  __shared__ __align__(16) float bufA[64*68];   // zs [point][ch]
  __shared__ __align__(16) float bufB[64*68];   // ds [point][ch]
  __shared__ __align__(16) unsigned short sb[64*136]; // x split -> e1out split
  __shared__ int   ips[64*16];
  __shared__ float sx0[64], sx1[64], sx2[64], sxx[64];
  int bm = blockIdx.x;
  int tid = threadIdx.x, n = tid&63, s = tid>>6;
  int wid = tid>>6, lane = tid&63;
  int l15 = lane&15, q = lane>>4;
  if(s==0){
    const float* xp = xyz + (size_t)(bm*64+n)*3;
    float px=xp[0], py=xp[1], pz=xp[2];
    sx0[n]=px; sx1[n]=py; sx2[n]=pz; sxx[n]=px*px+py*py+pz*pz;
  }
  __syncthreads();
  // ---- phase 1: top-16 (8 waves x 8 points; 8 lanes/point x 8 candidates) --
  {
    int p = lane>>3, seg = lane&7;
    int n1 = wid*8 + p;
    float px=sx0[n1], py=sx1[n1], pz=sx2[n1], xxn=sxx[n1];
    float pdr[8];
    #pragma unroll
    for(int t=0;t<8;t++){
      int m = seg*8+t;
      pdr[t] = 2.f*(px*sx0[m]+py*sx1[m]+pz*sx2[m]) - xxn - sxx[m];
    }
    for(int j=0;j<16;j++){
      float bv=-3.4e38f; int bi=seg*8;
      #pragma unroll
      for(int t=0;t<8;t++){ if(pdr[t]>bv){bv=pdr[t]; bi=seg*8+t;} }  // strict >: lowest idx
      float ov; int oi;
      ov=__shfl_xor(bv,1); oi=__shfl_xor(bi,1);
      if(ov>bv || (ov==bv && oi<bi)){bv=ov;bi=oi;}
      ov=__shfl_xor(bv,2); oi=__shfl_xor(bi,2);
      if(ov>bv || (ov==bv && oi<bi)){bv=ov;bi=oi;}
      ov=__shfl_xor(bv,4); oi=__shfl_xor(bi,4);
      if(ov>bv || (ov==bv && oi<bi)){bv=ov;bi=oi;}
      if(seg==0) ips[n1*16+j]=bi;
      if((bi>>3)==seg) pdr[bi&7]=-3.4e38f;
    }
  }
  // ---- phase 2: split x into sb (8 s-groups x 8 channels) ----
  {
    unsigned short* r = sb + n*136;
    if(s==0){
      float px=sx0[n], py=sx1[n], pz=sx2[n];
      unsigned short h;
      h=f2bs(px); r[0]=h; r[64]=f2bs(px-bs2f(h));
      h=f2bs(py); r[1]=h; r[65]=f2bs(py-bs2f(h));
      h=f2bs(pz); r[2]=h; r[66]=f2bs(pz-bs2f(h));
    }
    const float* fp = feats + (size_t)(bm*64+n)*61;
    #pragma unroll
    for(int t=0;t<8;t++){
      int cc = s*8+t;
      if(cc<61){
        float v=fp[cc]; unsigned short h=f2bs(v);
        r[3+cc]=h; r[64+3+cc]=f2bs(v-bs2f(h));
      }
    }
  }
  __syncthreads();
  // ---- phase 3: edge1 MFMA (8 waves x 16 weight-rows) ----
  {
    int rbase = wid*16;
    f32x4 acc[4];
    #pragma unroll
    for(int d=0;d<4;d++) acc[d]=(f32x4){0.f,0.f,0.f,0.f};
    #pragma unroll
    for(int kc=0;kc<2;kc++){
      int k0=kc*32;
      size_t a0=(size_t)(rbase+l15)*64 + k0 + q*8;
      bf16x8 a0h=*(const bf16x8*)(W1h+a0), a0l=*(const bf16x8*)(W1l+a0);
      #pragma unroll
      for(int nt=0;nt<4;nt++){
        int row = nt*16 + l15;
        bf16x8 bh = *(const bf16x8*)&sb[row*136 + k0 + q*8];
        bf16x8 bl = *(const bf16x8*)&sb[row*136 + 64 + k0 + q*8];
        acc[nt]=MF(a0h,bh,acc[nt]);
        acc[nt]=MF(a0h,bl,acc[nt]);
        acc[nt]=MF(a0l,bh,acc[nt]);
      }
    }
    __syncthreads();
    float* dst = (wid<4)? bufA : bufB;
    int ro = (wid&3)*16;
    // transposed store: [point n][channel o], o-quad contiguous -> f32x4
    #pragma unroll
    for(int nt=0;nt<4;nt++)
      *(f32x4*)&dst[(nt*16+l15)*68 + ro + q*4] = acc[nt];
  }
  __syncthreads();
  // ---- phase 4: gather edge1 (float4 along ch); write cats + sb ----
  {
    #pragma unroll
    for(int it=0; it<2; ++it){
      int item = tid + it*512;
      int nn = item>>4, o0 = (item&15)*4;
      const int* ip = &ips[nn*16];
      f32x4 mz = {-3.4e38f,-3.4e38f,-3.4e38f,-3.4e38f};
      #pragma unroll
      for(int k=0;k<16;k++){
        f32x4 z = *(const f32x4*)&bufA[ip[k]*68 + o0];
        mz[0]=fmaxf(mz[0],z[0]); mz[1]=fmaxf(mz[1],z[1]);
        mz[2]=fmaxf(mz[2],z[2]); mz[3]=fmaxf(mz[3],z[3]);
      }
      f32x4 d = *(const f32x4*)&bufB[nn*68 + o0];
      float4 sg = *(const float4*)&g1[o0];
      float4 bb = *(const float4*)&b1[o0];
      float v[4];
      v[0]=fmaxf(sg.x*BNS*(mz[0]+d[0])+bb.x,0.f);
      v[1]=fmaxf(sg.y*BNS*(mz[1]+d[1])+bb.y,0.f);
      v[2]=fmaxf(sg.z*BNS*(mz[2]+d[2])+bb.z,0.f);
      v[3]=fmaxf(sg.w*BNS*(mz[3]+d[3])+bb.w,0.f);
      unsigned short hv[4], lv[4];
      #pragma unroll
      for(int c=0;c<4;c++){ hv[c]=f2bs(v[c]); lv[c]=f2bs(v[c]-bs2f(hv[c])); }
      ushort4 hq=make_ushort4(hv[0],hv[1],hv[2],hv[3]);
      ushort4 lq=make_ushort4(lv[0],lv[1],lv[2],lv[3]);
      size_t cb = ((size_t)bm*64+nn)*384 + o0;
      *(ushort4*)&cat[cb] = hq; *(ushort4*)&cat[cb+192] = lq;
      *(ushort4*)&sb[nn*136 + o0] = hq;        // x dead after phase 3
      *(ushort4*)&sb[nn*136 + 64 + o0] = lq;
    }
  }
  // ---- phase 5: edge2 (2 chunks of 64 o) from sb ----
  for(int ch=0; ch<2; ch++){
    __syncthreads();
    int wrow = ((wid<4)?0:128) + ch*64 + (wid&3)*16;
    f32x4 acc[4];
    #pragma unroll
    for(int d=0;d<4;d++) acc[d]=(f32x4){0.f,0.f,0.f,0.f};
    #pragma unroll
    for(int kc=0;kc<2;kc++){
      int k0=kc*32;
      size_t a0=(size_t)(wrow+l15)*64 + k0 + q*8;
      bf16x8 a0h=*(const bf16x8*)(W2h+a0), a0l=*(const bf16x8*)(W2l+a0);
      #pragma unroll
      for(int nt=0;nt<4;nt++){
        int row = nt*16 + l15;
        bf16x8 bh = *(const bf16x8*)&sb[row*136 + k0 + q*8];
        bf16x8 bl = *(const bf16x8*)&sb[row*136 + 64 + k0 + q*8];
        acc[nt]=MF(a0h,bh,acc[nt]);
        acc[nt]=MF(a0h,bl,acc[nt]);
        acc[nt]=MF(a0l,bh,acc[nt]);
      }
    }
    __syncthreads();
    float* dst = (wid<4)? bufA : bufB;
    int ro = (wid&3)*16;
    #pragma unroll
    for(int nt=0;nt<4;nt++)
      *(f32x4*)&dst[(nt*16+l15)*68 + ro + q*4] = acc[nt];
    __syncthreads();
    #pragma unroll
    for(int it=0; it<2; ++it){
      int item = tid + it*512;
      int nn = item>>4, o0 = (item&15)*4;
      const int* ip = &ips[nn*16];
      f32x4 mz = {-3.4e38f,-3.4e38f,-3.4e38f,-3.4e38f};
      #pragma unroll
      for(int k=0;k<16;k++){
        f32x4 z = *(const f32x4*)&bufA[ip[k]*68 + o0];
        mz[0]=fmaxf(mz[0],z[0]); mz[1]=fmaxf(mz[1],z[1]);
        mz[2]=fmaxf(mz[2],z[2]); mz[3]=fmaxf(mz[3],z[3]);
      }
      f32x4 d = *(const f32x4*)&bufB[nn*68 + o0];
      float4 sg = *(const float4*)&g2[ch*64+o0];
      float4 bb = *(const float4*)&b2[ch*64+o0];
      float v[4];
      v[0]=fmaxf(sg.x*BNS*(mz[0]+d[0])+bb.x,0.f);
      v[1]=fmaxf(sg.y*BNS*(mz[1]+d[1])+bb.y,0.f);
      v[2]=fmaxf(sg.z*BNS*(mz[2]+d[2])+bb.z,0.f);
      v[3]=fmaxf(sg.w*BNS*(mz[3]+d[3])+bb.w,0.f);
      unsigned short hv[4], lv[4];
      #pragma unroll
      for(int c=0;c<4;c++){ hv[c]=f2bs(v[c]); lv[c]=f2bs(v[c]-bs2f(hv[c])); }
      size_t cb = ((size_t)bm*64+nn)*384 + 64 + ch*64 + o0;
      *(ushort4*)&cat[cb]     = make_ushort4(hv[0],hv[1],hv[2],hv[3]);
      *(ushort4*)&cat[cb+192] = make_ushort4(lv[0],lv[1],lv[2],lv[3]);
    }
  }
}

// ------- fused MLP: cal1 -> cal2 -> gate -> exp1 -> exp2 -> pool ------------
// One block per bm group (64 rows), 512 threads. LDS overlay = 80 KB
// (2 blocks/CU). Proven round-5 structure (74 us).
__global__ __launch_bounds__(512,4) void k_mlp(
    const unsigned short* __restrict__ Whi, const unsigned short* __restrict__ Wlo,
    const unsigned short* __restrict__ cats,
    const float* __restrict__ c1g, const float* __restrict__ c1b,
    const float* __restrict__ c2bias,
    const float* __restrict__ e1g, const float* __restrict__ e1b,
    const float* __restrict__ e2g, const float* __restrict__ e2b,
    float* __restrict__ pool){
  __shared__ __align__(16) unsigned short buf[8*4096];
  __shared__ __align__(16) unsigned short calB[2*4096];
  int bm = blockIdx.x;
  int tid = threadIdx.x, wid = tid>>6, lane = tid&63;
  int l15 = lane&15, q = lane>>4;

  // ---- issue cal1 kc=0 weight loads before staging (hide behind barrier) --
  const unsigned short* w1h = Whi + 24576;
  const unsigned short* w1l = Wlo + 24576;
  int c1ot = wid>>1, c1rh = wid&1;
  size_t c1wo0 = (size_t)(c1ot*16+l15)*192 + q*8;
  bf16x8 cah = *(const bf16x8*)(w1h+c1wo0);
  bf16x8 cal_ = *(const bf16x8*)(w1l+c1wo0);

  // ---- stage X (split, chunked+swizzled) into buf[0..5] ----
  size_t xb = (size_t)bm*24576;  // 64*384
  #pragma unroll
  for(int i=0;i<6;i++){
    int U = tid + i*512;
    int kc = U>>9, w = U&511, rr = w>>3, up = w&7, u = up ^ (rr&7);
    const unsigned short* src = cats + xb + (size_t)rr*384
      + (u<4 ? (kc*32 + u*8) : (192 + kc*32 + (u-4)*8));
    *(uint4*)&buf[kc*4096 + w*8] = *(const uint4*)src;
  }
  __syncthreads();

  // ---- cal1: out 64, K=192 -> calB; weight rotation, prio'd MFMA ----
  f32x4 a0={0.f,0.f,0.f,0.f}, a1={0.f,0.f,0.f,0.f};
  {
    int r0 = c1rh*32+l15, r1 = c1rh*32+16+l15;
    __builtin_amdgcn_s_setprio(1);
    #pragma unroll
    for(int kc=0;kc<6;kc++){
      bf16x8 nah, nal;
      if(kc<5){
        size_t wo = c1wo0 + (kc+1)*32;
        nah=*(const bf16x8*)(w1h+wo); nal=*(const bf16x8*)(w1l+wo);
      }
      const unsigned short* cb = buf + kc*4096;
      bf16x8 xh0=*(const bf16x8*)&cb[(r0*8+((  q)^(r0&7)))*8];
      bf16x8 xl0=*(const bf16x8*)&cb[(r0*8+((4+q)^(r0&7)))*8];
      bf16x8 xh1=*(const bf16x8*)&cb[(r1*8+((  q)^(r1&7)))*8];
      bf16x8 xl1=*(const bf16x8*)&cb[(r1*8+((4+q)^(r1&7)))*8];
      a0=MF(cah,xh0,a0); a1=MF(cah,xh1,a1);
      a0=MF(cah,xl0,a0); a1=MF(cah,xl1,a1);
      a0=MF(cal_,xh0,a0); a1=MF(cal_,xh1,a1);
      cah=nah; cal_=nal;
    }
    __builtin_amdgcn_s_setprio(0);
  }
  // ---- prefetch cal2 kc=0 weights (overlaps cal1 epilogue + barrier) ----
  const unsigned short* w2h = Whi + 36864;
  const unsigned short* w2l = Wlo + 36864;
  bf16x8 c2h[6], c2l[6];
  #pragma unroll
  for(int i=0;i<6;i++){
    int ot = (wid*6+i)>>2;
    size_t wo=(size_t)(ot*16+l15)*64 + q*8;
    c2h[i]=*(const bf16x8*)(w2h+wo); c2l[i]=*(const bf16x8*)(w2l+wo);
  }
  // ---- cal1 epilogue (vectorized) ----
  {
    int c0 = c1ot*16+q*4;
    float4 sg = *(const float4*)&c1g[c0];
    float4 bb = *(const float4*)&c1b[c0];
    float v0[4], v1[4];
    v0[0]=fmaxf(a0[0]*sg.x*BNS+bb.x,0.f); v1[0]=fmaxf(a1[0]*sg.x*BNS+bb.x,0.f);
    v0[1]=fmaxf(a0[1]*sg.y*BNS+bb.y,0.f); v1[1]=fmaxf(a1[1]*sg.y*BNS+bb.y,0.f);
    v0[2]=fmaxf(a0[2]*sg.z*BNS+bb.z,0.f); v1[2]=fmaxf(a1[2]*sg.z*BNS+bb.z,0.f);
    v0[3]=fmaxf(a0[3]*sg.w*BNS+bb.w,0.f); v1[3]=fmaxf(a1[3]*sg.w*BNS+bb.w,0.f);
    put_split4(calB, c1rh*32+l15,    c0, v0);
    put_split4(calB, c1rh*32+16+l15, c0, v1);
  }
  __syncthreads();
  // ---- cal2: out 192, K=64 (calB); then sigmoid gate -> buf in place ----
  f32x4 ac[6];
  #pragma unroll
  for(int i=0;i<6;i++) ac[i]=(f32x4){0.f,0.f,0.f,0.f};
  #pragma unroll
  for(int kc=0;kc<2;kc++){
    const unsigned short* cb = calB + kc*4096;
    if(kc==1){
      #pragma unroll
      for(int i=0;i<6;i++){
        int ot = (wid*6+i)>>2;
        size_t wo=(size_t)(ot*16+l15)*64 + 32 + q*8;
        c2h[i]=*(const bf16x8*)(w2h+wo); c2l[i]=*(const bf16x8*)(w2l+wo);
      }
    }
    __builtin_amdgcn_s_setprio(1);
    #pragma unroll
    for(int i=0;i<6;i++){
      int nf=(wid*6+i)&3;
      int r=nf*16+l15;
      bf16x8 xh=*(const bf16x8*)&cb[(r*8+((  q)^(r&7)))*8];
      bf16x8 xl=*(const bf16x8*)&cb[(r*8+((4+q)^(r&7)))*8];
      ac[i]=MF(c2h[i],xh,ac[i]); ac[i]=MF(c2h[i],xl,ac[i]); ac[i]=MF(c2l[i],xh,ac[i]);
    }
    __builtin_amdgcn_s_setprio(0);
  }
  // ---- prefetch exp1 kc=0 weights (overlaps gate) ----
  const unsigned short* e1wh=Whi+49152; const unsigned short* e1wl=Wlo+49152;
  int ob1 = wid*32;
  bf16x8 p1h[2], p1l[2];
  #pragma unroll
  for(int mt=0;mt<2;mt++){
    size_t wo=(size_t)(ob1+mt*16+l15)*192 + q*8;
    p1h[mt]=*(const bf16x8*)(e1wh+wo); p1l[mt]=*(const bf16x8*)(e1wl+wo);
  }
  // ---- gate (vectorized RMW) ----
  #pragma unroll
  for(int i=0;i<6;i++){
    int j=wid*6+i, ot=j>>2, nf=j&3, n=nf*16+l15;
    int c0=ot*16+q*4;
    float4 cb4 = *(const float4*)&c2bias[c0];
    float xv[4];
    get_split4(buf, n, c0, xv);
    xv[0] *= 1.f/(1.f+__expf(-(ac[i][0]+cb4.x)));
    xv[1] *= 1.f/(1.f+__expf(-(ac[i][1]+cb4.y)));
    xv[2] *= 1.f/(1.f+__expf(-(ac[i][2]+cb4.z)));
    xv[3] *= 1.f/(1.f+__expf(-(ac[i][3]+cb4.w)));
    put_split4(buf, n, c0, xv);
  }
  __syncthreads();
  // ---- exp1: out 256, K=192; regs accumulate, then overwrite buf ----
  {
    f32x4 e1a[2][4];
    #pragma unroll
    for(int a=0;a<2;a++)
      #pragma unroll
      for(int d=0;d<4;d++) e1a[a][d]=(f32x4){0.f,0.f,0.f,0.f};
    __builtin_amdgcn_s_setprio(1);
    #pragma unroll
    for(int kc=0;kc<6;kc++){
      bf16x8 nh[2], nl[2];
      if(kc<5){
        #pragma unroll
        for(int mt=0;mt<2;mt++){
          size_t wo=(size_t)(ob1+mt*16+l15)*192 + (kc+1)*32 + q*8;
          nh[mt]=*(const bf16x8*)(e1wh+wo); nl[mt]=*(const bf16x8*)(e1wl+wo);
        }
      }
      const unsigned short* cb = buf + kc*4096;
      #pragma unroll
      for(int nf=0;nf<4;nf++){
        int r=nf*16+l15;
        bf16x8 xh=*(const bf16x8*)&cb[(r*8+((  q)^(r&7)))*8];
        bf16x8 xl=*(const bf16x8*)&cb[(r*8+((4+q)^(r&7)))*8];
        e1a[0][nf]=MF(p1h[0],xh,e1a[0][nf]); e1a[1][nf]=MF(p1h[1],xh,e1a[1][nf]);
        e1a[0][nf]=MF(p1h[0],xl,e1a[0][nf]); e1a[1][nf]=MF(p1h[1],xl,e1a[1][nf]);
        e1a[0][nf]=MF(p1l[0],xh,e1a[0][nf]); e1a[1][nf]=MF(p1l[1],xh,e1a[1][nf]);
      }
      p1h[0]=nh[0]; p1h[1]=nh[1]; p1l[0]=nl[0]; p1l[1]=nl[1];
    }
    __builtin_amdgcn_s_setprio(0);
    __syncthreads();   // all reads of X retired; buf is now free
    // prefetch exp2 kc=0 weights (overlaps exp1 epilogue + barrier)
    const unsigned short* e2wh=Whi+98304; const unsigned short* e2wl=Wlo+98304;
    int ob2 = wid*64;
    bf16x8 p2h[4], p2l[4];
    #pragma unroll
    for(int mt=0;mt<4;mt++){
      size_t wo=(size_t)(ob2+mt*16+l15)*256 + q*8;
      p2h[mt]=*(const bf16x8*)(e2wh+wo); p2l[mt]=*(const bf16x8*)(e2wl+wo);
    }
    // exp1 epilogue (vectorized)
    #pragma unroll
    for(int mt=0;mt<2;mt++){
      int c0 = ob1+mt*16+q*4;
      float4 sg = *(const float4*)&e1g[c0];
      float4 bb = *(const float4*)&e1b[c0];
      #pragma unroll
      for(int nf=0;nf<4;nf++){
        float v[4];
        v[0]=fmaxf(e1a[mt][nf][0]*sg.x*BNS+bb.x,0.f);
        v[1]=fmaxf(e1a[mt][nf][1]*sg.y*BNS+bb.y,0.f);
        v[2]=fmaxf(e1a[mt][nf][2]*sg.z*BNS+bb.z,0.f);
        v[3]=fmaxf(e1a[mt][nf][3]*sg.w*BNS+bb.w,0.f);
        put_split4(buf, nf*16+l15, c0, v);
      }
    }
    __syncthreads();
    // ---- exp2: out 512, K=256; bn -> max-pool over 64 rows ----
    f32x4 a2[4][4];
    #pragma unroll
    for(int a=0;a<4;a++)
      #pragma unroll
      for(int d=0;d<4;d++) a2[a][d]=(f32x4){0.f,0.f,0.f,0.f};
    {  // kc = 0 (prefetched weights)
      const unsigned short* cb = buf;
      __builtin_amdgcn_s_setprio(1);
      #pragma unroll
      for(int nf=0;nf<4;nf++){
        int r=nf*16+l15;
        bf16x8 xh=*(const bf16x8*)&cb[(r*8+((  q)^(r&7)))*8];
        bf16x8 xl=*(const bf16x8*)&cb[(r*8+((4+q)^(r&7)))*8];
        #pragma unroll
        for(int mt=0;mt<4;mt++) a2[mt][nf]=MF(p2h[mt],xh,a2[mt][nf]);
        #pragma unroll
        for(int mt=0;mt<4;mt++) a2[mt][nf]=MF(p2h[mt],xl,a2[mt][nf]);
        #pragma unroll
        for(int mt=0;mt<4;mt++) a2[mt][nf]=MF(p2l[mt],xh,a2[mt][nf]);
      }
      __builtin_amdgcn_s_setprio(0);
    }
    for(int kc=1;kc<8;kc++){
      bf16x8 ch[4], cl[4];
      #pragma unroll
      for(int mt=0;mt<4;mt++){
        size_t wo=(size_t)(ob2+mt*16+l15)*256 + kc*32 + q*8;
        ch[mt]=*(const bf16x8*)(e2wh+wo); cl[mt]=*(const bf16x8*)(e2wl+wo);
      }
      const unsigned short* cb = buf + kc*4096;
      __builtin_amdgcn_s_setprio(1);
      #pragma unroll
      for(int nf=0;nf<4;nf++){
        int r=nf*16+l15;
        bf16x8 xh=*(const bf16x8*)&cb[(r*8+((  q)^(r&7)))*8];
        bf16x8 xl=*(const bf16x8*)&cb[(r*8+((4+q)^(r&7)))*8];
        #pragma unroll
        for(int mt=0;mt<4;mt++) a2[mt][nf]=MF(ch[mt],xh,a2[mt][nf]);
        #pragma unroll
        for(int mt=0;mt<4;mt++) a2[mt][nf]=MF(ch[mt],xl,a2[mt][nf]);
      }
      #pragma unroll
      for(int nf=0;nf<4;nf++){
        int r=nf*16+l15;
        bf16x8 xh=*(const bf16x8*)&cb[(r*8+((  q)^(r&7)))*8];
        #pragma unroll
        for(int mt=0;mt<4;mt++) a2[mt][nf]=MF(cl[mt],xh,a2[mt][nf]);
      }
      __builtin_amdgcn_s_setprio(0);
    }
    int b = bm>>8, m = bm&255;
    #pragma unroll
    for(int mt=0;mt<4;mt++){
      int c0 = ob2+mt*16+q*4;
      float4 sg = *(const float4*)&e2g[c0];
      float4 bb = *(const float4*)&e2b[c0];
      float s[4]={sg.x*BNS,sg.y*BNS,sg.z*BNS,sg.w*BNS};
      float bbv[4]={bb.x,bb.y,bb.z,bb.w};
      #pragma unroll
      for(int rr=0;rr<4;rr++){
        float v = a2[mt][0][rr]*s[rr]+bbv[rr];
        v = fmaxf(v, a2[mt][1][rr]*s[rr]+bbv[rr]);
        v = fmaxf(v, a2[mt][2][rr]*s[rr]+bbv[rr]);
        v = fmaxf(v, a2[mt][3][rr]*s[rr]+bbv[rr]);
        v = fmaxf(v, 0.f);
        v = fmaxf(v, __shfl_xor(v,1));
        v = fmaxf(v, __shfl_xor(v,2));
        v = fmaxf(v, __shfl_xor(v,4));
        v = fmaxf(v, __shfl_xor(v,8));
        if(l15==0) pool[((size_t)b*512 + c0+rr)*256 + m] = v;
      }
    }
  }
}

// ------- fused head: red -> sc1 -> sc2, one block = (b, 2 cols) -------------
// 1024 threads: K-dim split across 4 quarters (h), LDS partial combine.
__global__ __launch_bounds__(1024) void k_headf(const float* __restrict__ Wt_red,
    const float* __restrict__ Wt_s1, const float* __restrict__ Wt_s2,
    const float* __restrict__ pool, float* __restrict__ Og,
    const float* __restrict__ red_g, const float* __restrict__ red_b,
    const float* __restrict__ n1g, const float* __restrict__ n1b,
    const float* __restrict__ s1b, const float* __restrict__ s2b,
    const float* __restrict__ n2g, const float* __restrict__ n2b){
  __shared__ float P[512*3];
  __shared__ float X1[256*3];
  __shared__ float H[256*3];
  __shared__ float PB[256*9];
  int g = blockIdx.x;
  int b = g>>7, mg = g&127;
  int m0 = mg*2;
  int tid = threadIdx.x;
  int o = tid&255, h = tid>>8;   // h in 0..3
  if(tid<512){
    int c = tid;
    float2 v = *(const float2*)&pool[((size_t)b*512+c)*256 + m0];
    P[c*3+0]=v.x; P[c*3+1]=v.y;
  }
  __syncthreads();
  float a0=0.f, a1=0.f;
  // red: K=512, quarter per h
  {
    int c0 = h*128;
    #pragma unroll 8
    for(int i=0;i<128;i++){
      int c = c0+i;
      float w = Wt_red[c*256+o];
      a0 += w*P[c*3]; a1 += w*P[c*3+1];
    }
  }
  PB[o*9+h*2]=a0; PB[o*9+h*2+1]=a1;
  __syncthreads();
  a0 = (PB[o*9+0]+PB[o*9+2])+(PB[o*9+4]+PB[o*9+6]);
  a1 = (PB[o*9+1]+PB[o*9+3])+(PB[o*9+5]+PB[o*9+7]);
  float x0r,x1r;
  {
    float s=red_g[o]*BNS, bi=red_b[o], s1=n1g[o]*BNS, b1=n1b[o];
    float r0=fmaxf(a0*s+bi,0.f), r1=fmaxf(a1*s+bi,0.f);
    x0r=2.f*r0*s1+b1; x1r=2.f*r1*s1+b1;
    if(h==0){ X1[o*3]=x0r; X1[o*3+1]=x1r; }
  }
  __syncthreads();
  // sc1: K=256, quarters of 64
  a0=0.f; a1=0.f;
  {
    int c0 = h*64;
    #pragma unroll 8
    for(int i=0;i<64;i++){
      int c = c0+i;
      float w = Wt_s1[c*256+o];
      a0 += w*X1[c*3]; a1 += w*X1[c*3+1];
    }
  }
  PB[o*9+h*2]=a0; PB[o*9+h*2+1]=a1;
  __syncthreads();
  a0 = (PB[o*9+0]+PB[o*9+2])+(PB[o*9+4]+PB[o*9+6]);
  a1 = (PB[o*9+1]+PB[o*9+3])+(PB[o*9+5]+PB[o*9+7]);
  {
    float bi=s1b[o];
    if(h==0){ H[o*3]=fmaxf(a0+bi,0.f); H[o*3+1]=fmaxf(a1+bi,0.f); }
  }
  __syncthreads();
  // sc2 + residual + bn2
  a0=0.f; a1=0.f;
  {
    int c0 = h*64;
    #pragma unroll 8
    for(int i=0;i<64;i++){
      int c = c0+i;
      float w = Wt_s2[c*256+o];
      a0 += w*H[c*3]; a1 += w*H[c*3+1];
    }
  }
  PB[o*9+h*2]=a0; PB[o*9+h*2+1]=a1;
  __syncthreads();
  if(h==0){
    a0 = (PB[o*9+0]+PB[o*9+2])+(PB[o*9+4]+PB[o*9+6]);
    a1 = (PB[o*9+1]+PB[o*9+3])+(PB[o*9+5]+PB[o*9+7]);
    float bi=s2b[o], s2=n2g[o]*BNS, b2=n2b[o];
    float v0=(x0r+a0+bi)*s2+b2, v1=(x1r+a1+bi)*s2+b2;
    *(float2*)&Og[((size_t)b*256+o)*256 + m0] = make_float2(v0,v1);
  }
}

extern "C" void kernel_launch(void* const* d_in, const int* in_sizes, int n_in,
                              void* d_out, int out_size, void* d_ws, size_t ws_size,
                              hipStream_t stream){
  const float* xyz     =(const float*)d_in[0];
  const float* feats   =(const float*)d_in[1];
  const float* e1_w    =(const float*)d_in[2];
  const float* e1_g    =(const float*)d_in[3];
  const float* e1_b    =(const float*)d_in[4];
  const float* e2_w    =(const float*)d_in[5];
  const float* e2_g    =(const float*)d_in[6];
  const float* e2_b    =(const float*)d_in[7];
  const float* cal1_w  =(const float*)d_in[8];
  const float* cal1_g  =(const float*)d_in[9];
  const float* cal1_b  =(const float*)d_in[10];
  const float* cal2_w  =(const float*)d_in[11];
  const float* cal2_bias=(const float*)d_in[12];
  const float* exp1_w  =(const float*)d_in[13];
  const float* exp1_g  =(const float*)d_in[14];
  const float* exp1_b  =(const float*)d_in[15];
  const float* exp2_w  =(const float*)d_in[16];
  const float* exp2_g  =(const float*)d_in[17];
  const float* exp2_b  =(const float*)d_in[18];
  const float* red_w   =(const float*)d_in[19];
  const float* red_g   =(const float*)d_in[20];
  const float* red_b   =(const float*)d_in[21];
  const float* sc1_w   =(const float*)d_in[22];
  const float* sc1_b   =(const float*)d_in[23];
  const float* sc2_w   =(const float*)d_in[24];
  const float* sc2_b   =(const float*)d_in[25];
  const float* sc_n1_g =(const float*)d_in[26];
  const float* sc_n1_b =(const float*)d_in[27];
  const float* sc_n2_g =(const float*)d_in[28];
  const float* sc_n2_b =(const float*)d_in[29];

  char* wsb=(char*)d_ws;
  unsigned short* cats=(unsigned short*)(wsb + 10485760);         // 24 MB [row][2][192]
  float*          pool=(float*)         (wsb + 69206016);         // 1 MB
  unsigned short* Whi =(unsigned short*)(wsb + 75497472);         // 448 KB
  unsigned short* Wlo =(unsigned short*)(wsb + 76021760);         // 448 KB
  float*          Wt_red=(float*)       (wsb + 76546048);         // 512 KB
  float*          Wt_s1 =(float*)       (wsb + 77070336);         // 256 KB
  float*          Wt_s2 =(float*)       (wsb + 77332480);         // 256 KB
  unsigned short* e1e_h=Whi;          unsigned short* e1e_l=Wlo;          // 128x64
  unsigned short* e2e_h=Whi+8192;     unsigned short* e2e_l=Wlo+8192;     // 256x64

  k_prep      <<<1152,256,0,stream>>>(e1_w,e2_w,cal1_w,cal2_w,exp1_w,exp2_w,Whi,Wlo,
                                      red_w,sc1_w,sc2_w,Wt_red,Wt_s1,Wt_s2);
  k_knne12    <<<512,512,0,stream>>>(xyz,feats,e1e_h,e1e_l,e2e_h,e2e_l,
                                     e1_g,e1_b,e2_g,e2_b,cats);
  k_mlp       <<<512,512,0,stream>>>(Whi,Wlo,cats,cal1_g,cal1_b,cal2_bias,
                                     exp1_g,exp1_b,exp2_g,exp2_b,pool);
  k_headf     <<<256,1024,0,stream>>>(Wt_red,Wt_s1,Wt_s2,pool,(float*)d_out,
                                      red_g,red_b,sc_n1_g,sc_n1_b,sc1_b,sc2_b,sc_n2_g,sc_n2_b);
}

// Round 10
// 237.415 us; speedup vs baseline: 1.0341x; 1.0341x over previous
//
#include <hip/hip_runtime.h>
#include <hip/hip_bf16.h>
#include <math.h>
#include <stddef.h>

#define DEV __device__ __forceinline__
__device__ const float BNS = 0.99999500003749968f; // 1/sqrt(1+1e-5)

typedef __bf16 bf16x8 __attribute__((ext_vector_type(8)));
typedef float  f32x4  __attribute__((ext_vector_type(4)));

#define MF(a,b,c) __builtin_amdgcn_mfma_f32_16x16x32_bf16(a,b,c,0,0,0)

DEV unsigned short f2bs(float v){
  union{ __hip_bfloat16 b; unsigned short u; } c; c.b=__float2bfloat16(v); return c.u;
}
DEV float bs2f(unsigned short u){
  union{ unsigned short u; __hip_bfloat16 b; } c; c.u=u; return __bfloat162float(c.b);
}

// Chunked split-bf16 LDS layout: chunk cc covers channels [cc*32, cc*32+32),
// 64 rows x 64 ushorts (32 hi + 32 lo), XOR-swizzled like the GEMM staging:
// unit up = u ^ (row&7), u<4 = hi k-offset u*8, u>=4 = lo.
// Channel quads c0..c0+3 (c0 % 4 == 0) are CONTIGUOUS ushorts -> vector ops.
DEV void put_split4(unsigned short* chunks, int n, int c0, const float* v){
  int cc=c0>>5, u=(c0>>3)&3, e=c0&7;          // e in {0,4}
  unsigned short* base = chunks + cc*4096;
  unsigned short h0=f2bs(v[0]), h1=f2bs(v[1]), h2=f2bs(v[2]), h3=f2bs(v[3]);
  ushort4 hq = make_ushort4(h0,h1,h2,h3);
  ushort4 lq = make_ushort4(f2bs(v[0]-bs2f(h0)), f2bs(v[1]-bs2f(h1)),
                            f2bs(v[2]-bs2f(h2)), f2bs(v[3]-bs2f(h3)));
  *(ushort4*)&base[(n*8 + (u     ^ (n&7)))*8 + e] = hq;
  *(ushort4*)&base[(n*8 + ((u+4) ^ (n&7)))*8 + e] = lq;
}
DEV void get_split4(const unsigned short* chunks, int n, int c0, float* v){
  int cc=c0>>5, u=(c0>>3)&3, e=c0&7;
  const unsigned short* base = chunks + cc*4096;
  ushort4 hq = *(const ushort4*)&base[(n*8 + (u     ^ (n&7)))*8 + e];
  ushort4 lq = *(const ushort4*)&base[(n*8 + ((u+4) ^ (n&7)))*8 + e];
  v[0]=bs2f(hq.x)+bs2f(lq.x); v[1]=bs2f(hq.y)+bs2f(lq.y);
  v[2]=bs2f(hq.z)+bs2f(lq.z); v[3]=bs2f(hq.w)+bs2f(lq.w);
}

// Geometry: B=2, M=256 -> 512 bm groups, N=64 pts, KNN=16, CIN=64,
// edge1 O=64, edge2 O=128, SUMM=192, CALIB=64, EXP=256/512, OUT=256. f32 I/O.
// Split-bf16 activation layout in cats: [row][2][192] ushort (hi, lo).

// ------- fused prep: 6 weight splits + 3 head transposes in one launch ------
__global__ __launch_bounds__(256) void k_prep(const float* __restrict__ e1_w,
    const float* __restrict__ e2_w, const float* __restrict__ cal1_w,
    const float* __restrict__ cal2_w, const float* __restrict__ exp1_w,
    const float* __restrict__ exp2_w, unsigned short* __restrict__ Whi,
    unsigned short* __restrict__ Wlo,
    const float* __restrict__ red_w, const float* __restrict__ sc1_w,
    const float* __restrict__ sc2_w, float* __restrict__ Wt_red,
    float* __restrict__ Wt_s1, float* __restrict__ Wt_s2){
  __shared__ float s[32][33];
  int bid = blockIdx.x;
  if(bid < 896){
    const float* src; unsigned short *hi,*lo; int mode, O=0, i0;
    if(bid<32)      { src=e1_w;  hi=Whi;       lo=Wlo;       mode=1; O= 64; i0=bid*256; }
    else if(bid<96) { src=e2_w;  hi=Whi+8192;  lo=Wlo+8192;  mode=1; O=128; i0=(bid-32)*256; }
    else if(bid<144){ src=cal1_w;hi=Whi+24576; lo=Wlo+24576; mode=0;        i0=(bid-96)*256; }
    else if(bid<192){ src=cal2_w;hi=Whi+36864; lo=Wlo+36864; mode=0;        i0=(bid-144)*256; }
    else if(bid<384){ src=exp1_w;hi=Whi+49152; lo=Wlo+49152; mode=0;        i0=(bid-192)*256; }
    else            { src=exp2_w;hi=Whi+98304; lo=Wlo+98304; mode=0;        i0=(bid-384)*256; }
    int i = i0 + threadIdx.x;
    float v;
    if(mode==0) v = src[i];
    else { // edge rows: [W1 ; W2-W1] over [2O][64]
      int row=i>>6, c=i&63;
      v = (row<O) ? src[row*128+c] : (src[(row-O)*128+64+c]-src[(row-O)*128+c]);
    }
    unsigned short h=f2bs(v); hi[i]=h; lo[i]=f2bs(v-bs2f(h));
  } else {
    int lb = bid-896;
    const float* in; float* out; int O,K;
    if(lb<128){ in=red_w; out=Wt_red; O=256; K=512; }
    else if(lb<192){ in=sc1_w; out=Wt_s1; O=256; K=256; lb-=128; }
    else { in=sc2_w; out=Wt_s2; O=256; K=256; lb-=192; }
    int nt=O>>5;
    int to=lb%nt, tk=lb/nt;
    int c=threadIdx.x&31, r8=threadIdx.x>>5;
    #pragma unroll
    for(int p=0;p<4;p++){
      int r=r8+p*8;
      s[r][c]=in[(size_t)(to*32+r)*K + tk*32 + c];
    }
    __syncthreads();
    #pragma unroll
    for(int p=0;p<4;p++){
      int r=r8+p*8;
      out[(size_t)(tk*32+r)*O + to*32 + c]=s[c][r];
    }
  }
}

// -------- fused knn + edge1 + edge2: per bm, all in LDS ---------------------
// 512 threads / 8 waves; 56 KB LDS -> 2 blocks/CU. Round-7 structure
// (scalar gather, [ch][pt] bufs) + COALESCED feats staging: the 64x61 slab
// is loaded flat (lane-consecutive) and scattered to LDS, replacing the
// 244B-stride per-lane loads (~16x cache-line amplification).
__global__ __launch_bounds__(512) void k_knne12(const float* __restrict__ xyz,
    const float* __restrict__ feats,
    const unsigned short* __restrict__ W1h, const unsigned short* __restrict__ W1l,
    const unsigned short* __restrict__ W2h, const unsigned short* __restrict__ W2l,
    const float* __restrict__ g1, const float* __restrict__ b1,
    const float* __restrict__ g2, const float* __restrict__ b2,
    unsigned short* __restrict__ cat){
  __shared__ float bufA[64*65];   // zs [ch][pt]
  __shared__ float bufB[64*65];   // ds [ch][pt]
  __shared__ __align__(16) unsigned short sb[64*136]; // x split -> e1out split
  __shared__ int   ips[64*16];
  __shared__ float sx0[64], sx1[64], sx2[64], sxx[64];
  int bm = blockIdx.x;
  int tid = threadIdx.x, n = tid&63, s = tid>>6;
  int wid = tid>>6, lane = tid&63;
  int l15 = lane&15, q = lane>>4;
  if(s==0){
    const float* xp = xyz + (size_t)(bm*64+n)*3;
    float px=xp[0], py=xp[1], pz=xp[2];
    sx0[n]=px; sx1[n]=py; sx2[n]=pz; sxx[n]=px*px+py*py+pz*pz;
  }
  __syncthreads();
  // ---- phase 1: top-16 (8 waves x 8 points; 8 lanes/point x 8 candidates) --
  {
    int p = lane>>3, seg = lane&7;
    int n1 = wid*8 + p;
    float px=sx0[n1], py=sx1[n1], pz=sx2[n1], xxn=sxx[n1];
    float pdr[8];
    #pragma unroll
    for(int t=0;t<8;t++){
      int m = seg*8+t;
      pdr[t] = 2.f*(px*sx0[m]+py*sx1[m]+pz*sx2[m]) - xxn - sxx[m];
    }
    for(int j=0;j<16;j++){
      float bv=-3.4e38f; int bi=seg*8;
      #pragma unroll
      for(int t=0;t<8;t++){ if(pdr[t]>bv){bv=pdr[t]; bi=seg*8+t;} }  // strict >: lowest idx
      float ov; int oi;
      ov=__shfl_xor(bv,1); oi=__shfl_xor(bi,1);
      if(ov>bv || (ov==bv && oi<bi)){bv=ov;bi=oi;}
      ov=__shfl_xor(bv,2); oi=__shfl_xor(bi,2);
      if(ov>bv || (ov==bv && oi<bi)){bv=ov;bi=oi;}
      ov=__shfl_xor(bv,4); oi=__shfl_xor(bi,4);
      if(ov>bv || (ov==bv && oi<bi)){bv=ov;bi=oi;}
      if(seg==0) ips[n1*16+j]=bi;
      if((bi>>3)==seg) pdr[bi&7]=-3.4e38f;
    }
  }
  // ---- phase 2: split x into sb; feats loaded COALESCED ----
  {
    if(s==0){
      unsigned short* r = sb + n*136;
      float px=sx0[n], py=sx1[n], pz=sx2[n];
      unsigned short h;
      h=f2bs(px); r[0]=h; r[64]=f2bs(px-bs2f(h));
      h=f2bs(py); r[1]=h; r[65]=f2bs(py-bs2f(h));
      h=f2bs(pz); r[2]=h; r[66]=f2bs(pz-bs2f(h));
    }
    const float* fb = feats + (size_t)bm*64*61;
    #pragma unroll
    for(int i=0;i<8;i++){
      int idx = tid + i*512;          // 0..4095; 64*61 = 3904 valid
      if(idx<3904){
        float v = fb[idx];            // lane-consecutive -> coalesced
        int row = idx/61, cc = idx - row*61;
        unsigned short h=f2bs(v);
        sb[row*136 + 3+cc]      = h;
        sb[row*136 + 64 + 3+cc] = f2bs(v-bs2f(h));
      }
    }
  }
  __syncthreads();
  // ---- phase 3: edge1 MFMA (8 waves x 16 weight-rows) ----
  {
    int rbase = wid*16;
    f32x4 acc[4];
    #pragma unroll
    for(int d=0;d<4;d++) acc[d]=(f32x4){0.f,0.f,0.f,0.f};
    #pragma unroll
    for(int kc=0;kc<2;kc++){
      int k0=kc*32;
      size_t a0=(size_t)(rbase+l15)*64 + k0 + q*8;
      bf16x8 a0h=*(const bf16x8*)(W1h+a0), a0l=*(const bf16x8*)(W1l+a0);
      #pragma unroll
      for(int nt=0;nt<4;nt++){
        int row = nt*16 + l15;
        bf16x8 bh = *(const bf16x8*)&sb[row*136 + k0 + q*8];
        bf16x8 bl = *(const bf16x8*)&sb[row*136 + 64 + k0 + q*8];
        acc[nt]=MF(a0h,bh,acc[nt]);
        acc[nt]=MF(a0h,bl,acc[nt]);
        acc[nt]=MF(a0l,bh,acc[nt]);
      }
    }
    __syncthreads();
    float* dst = (wid<4)? bufA : bufB;
    int ro = (wid&3)*16;
    #pragma unroll
    for(int nt=0;nt<4;nt++)
      #pragma unroll
      for(int rr=0;rr<4;rr++)
        dst[(ro+q*4+rr)*65 + nt*16+l15] = acc[nt][rr];
  }
  __syncthreads();
  // ---- phase 4: gather edge1; write cats[0:64) + e1out split into sb ----
  {
    int o = lane;
    float sc = g1[o]*BNS, bi = b1[o];
    #pragma unroll 4
    for(int j=0;j<8;j++){
      int nn = wid*8 + j;
      const int* ip = &ips[nn*16];
      float mz = -3.4e38f;
      #pragma unroll
      for(int k=0;k<16;k++) mz = fmaxf(mz, bufA[o*65 + ip[k]]);
      float v = fmaxf(sc*(mz + bufB[o*65 + nn]) + bi, 0.f);
      unsigned short hv = f2bs(v), lv = f2bs(v - bs2f(hv));
      size_t cb = ((size_t)bm*64+nn)*384 + o;
      cat[cb] = hv; cat[cb+192] = lv;
      sb[nn*136 + o] = hv; sb[nn*136 + 64 + o] = lv;  // x dead after phase 3
    }
  }
  // ---- phase 5: edge2 (2 chunks of 64 o) from sb ----
  for(int ch=0; ch<2; ch++){
    __syncthreads();
    int wrow = ((wid<4)?0:128) + ch*64 + (wid&3)*16;
    f32x4 acc[4];
    #pragma unroll
    for(int d=0;d<4;d++) acc[d]=(f32x4){0.f,0.f,0.f,0.f};
    #pragma unroll
    for(int kc=0;kc<2;kc++){
      int k0=kc*32;
      size_t a0=(size_t)(wrow+l15)*64 + k0 + q*8;
      bf16x8 a0h=*(const bf16x8*)(W2h+a0), a0l=*(const bf16x8*)(W2l+a0);
      #pragma unroll
      for(int nt=0;nt<4;nt++){
        int row = nt*16 + l15;
        bf16x8 bh = *(const bf16x8*)&sb[row*136 + k0 + q*8];
        bf16x8 bl = *(const bf16x8*)&sb[row*136 + 64 + k0 + q*8];
        acc[nt]=MF(a0h,bh,acc[nt]);
        acc[nt]=MF(a0h,bl,acc[nt]);
        acc[nt]=MF(a0l,bh,acc[nt]);
      }
    }
    __syncthreads();
    float* dst = (wid<4)? bufA : bufB;
    int ro = (wid&3)*16;
    #pragma unroll
    for(int nt=0;nt<4;nt++)
      #pragma unroll
      for(int rr=0;rr<4;rr++)
        dst[(ro+q*4+rr)*65 + nt*16+l15] = acc[nt][rr];
    __syncthreads();
    int o = ch*64 + lane;
    float sc = g2[o]*BNS, bi = b2[o];
    #pragma unroll 4
    for(int j=0;j<8;j++){
      int nn = wid*8 + j;
      const int* ip = &ips[nn*16];
      float mz = -3.4e38f;
      #pragma unroll
      for(int k=0;k<16;k++) mz = fmaxf(mz, bufA[lane*65 + ip[k]]);
      float v = fmaxf(sc*(mz + bufB[lane*65 + nn]) + bi, 0.f);
      unsigned short hv = f2bs(v);
      size_t cb = ((size_t)bm*64+nn)*384 + 64 + o;
      cat[cb] = hv; cat[cb+192] = f2bs(v - bs2f(hv));
    }
  }
}

// ------- fused MLP: cal1 -> cal2 -> gate -> exp1 -> exp2 -> pool ------------
// One block per bm group (64 rows), 512 threads. LDS overlay = 80 KB
// (2 blocks/CU). Proven round-5 structure (74 us).
__global__ __launch_bounds__(512,4) void k_mlp(
    const unsigned short* __restrict__ Whi, const unsigned short* __restrict__ Wlo,
    const unsigned short* __restrict__ cats,
    const float* __restrict__ c1g, const float* __restrict__ c1b,
    const float* __restrict__ c2bias,
    const float* __restrict__ e1g, const float* __restrict__ e1b,
    const float* __restrict__ e2g, const float* __restrict__ e2b,
    float* __restrict__ pool){
  __shared__ __align__(16) unsigned short buf[8*4096];
  __shared__ __align__(16) unsigned short calB[2*4096];
  int bm = blockIdx.x;
  int tid = threadIdx.x, wid = tid>>6, lane = tid&63;
  int l15 = lane&15, q = lane>>4;

  // ---- issue cal1 kc=0 weight loads before staging (hide behind barrier) --
  const unsigned short* w1h = Whi + 24576;
  const unsigned short* w1l = Wlo + 24576;
  int c1ot = wid>>1, c1rh = wid&1;
  size_t c1wo0 = (size_t)(c1ot*16+l15)*192 + q*8;
  bf16x8 cah = *(const bf16x8*)(w1h+c1wo0);
  bf16x8 cal_ = *(const bf16x8*)(w1l+c1wo0);

  // ---- stage X (split, chunked+swizzled) into buf[0..5] ----
  size_t xb = (size_t)bm*24576;  // 64*384
  #pragma unroll
  for(int i=0;i<6;i++){
    int U = tid + i*512;
    int kc = U>>9, w = U&511, rr = w>>3, up = w&7, u = up ^ (rr&7);
    const unsigned short* src = cats + xb + (size_t)rr*384
      + (u<4 ? (kc*32 + u*8) : (192 + kc*32 + (u-4)*8));
    *(uint4*)&buf[kc*4096 + w*8] = *(const uint4*)src;
  }
  __syncthreads();

  // ---- cal1: out 64, K=192 -> calB; weight rotation, prio'd MFMA ----
  f32x4 a0={0.f,0.f,0.f,0.f}, a1={0.f,0.f,0.f,0.f};
  {
    int r0 = c1rh*32+l15, r1 = c1rh*32+16+l15;
    __builtin_amdgcn_s_setprio(1);
    #pragma unroll
    for(int kc=0;kc<6;kc++){
      bf16x8 nah, nal;
      if(kc<5){
        size_t wo = c1wo0 + (kc+1)*32;
        nah=*(const bf16x8*)(w1h+wo); nal=*(const bf16x8*)(w1l+wo);
      }
      const unsigned short* cb = buf + kc*4096;
      bf16x8 xh0=*(const bf16x8*)&cb[(r0*8+((  q)^(r0&7)))*8];
      bf16x8 xl0=*(const bf16x8*)&cb[(r0*8+((4+q)^(r0&7)))*8];
      bf16x8 xh1=*(const bf16x8*)&cb[(r1*8+((  q)^(r1&7)))*8];
      bf16x8 xl1=*(const bf16x8*)&cb[(r1*8+((4+q)^(r1&7)))*8];
      a0=MF(cah,xh0,a0); a1=MF(cah,xh1,a1);
      a0=MF(cah,xl0,a0); a1=MF(cah,xl1,a1);
      a0=MF(cal_,xh0,a0); a1=MF(cal_,xh1,a1);
      cah=nah; cal_=nal;
    }
    __builtin_amdgcn_s_setprio(0);
  }
  // ---- prefetch cal2 kc=0 weights (overlaps cal1 epilogue + barrier) ----
  const unsigned short* w2h = Whi + 36864;
  const unsigned short* w2l = Wlo + 36864;
  bf16x8 c2h[6], c2l[6];
  #pragma unroll
  for(int i=0;i<6;i++){
    int ot = (wid*6+i)>>2;
    size_t wo=(size_t)(ot*16+l15)*64 + q*8;
    c2h[i]=*(const bf16x8*)(w2h+wo); c2l[i]=*(const bf16x8*)(w2l+wo);
  }
  // ---- cal1 epilogue (vectorized) ----
  {
    int c0 = c1ot*16+q*4;
    float4 sg = *(const float4*)&c1g[c0];
    float4 bb = *(const float4*)&c1b[c0];
    float v0[4], v1[4];
    v0[0]=fmaxf(a0[0]*sg.x*BNS+bb.x,0.f); v1[0]=fmaxf(a1[0]*sg.x*BNS+bb.x,0.f);
    v0[1]=fmaxf(a0[1]*sg.y*BNS+bb.y,0.f); v1[1]=fmaxf(a1[1]*sg.y*BNS+bb.y,0.f);
    v0[2]=fmaxf(a0[2]*sg.z*BNS+bb.z,0.f); v1[2]=fmaxf(a1[2]*sg.z*BNS+bb.z,0.f);
    v0[3]=fmaxf(a0[3]*sg.w*BNS+bb.w,0.f); v1[3]=fmaxf(a1[3]*sg.w*BNS+bb.w,0.f);
    put_split4(calB, c1rh*32+l15,    c0, v0);
    put_split4(calB, c1rh*32+16+l15, c0, v1);
  }
  __syncthreads();
  // ---- cal2: out 192, K=64 (calB); then sigmoid gate -> buf in place ----
  f32x4 ac[6];
  #pragma unroll
  for(int i=0;i<6;i++) ac[i]=(f32x4){0.f,0.f,0.f,0.f};
  #pragma unroll
  for(int kc=0;kc<2;kc++){
    const unsigned short* cb = calB + kc*4096;
    if(kc==1){
      #pragma unroll
      for(int i=0;i<6;i++){
        int ot = (wid*6+i)>>2;
        size_t wo=(size_t)(ot*16+l15)*64 + 32 + q*8;
        c2h[i]=*(const bf16x8*)(w2h+wo); c2l[i]=*(const bf16x8*)(w2l+wo);
      }
    }
    __builtin_amdgcn_s_setprio(1);
    #pragma unroll
    for(int i=0;i<6;i++){
      int nf=(wid*6+i)&3;
      int r=nf*16+l15;
      bf16x8 xh=*(const bf16x8*)&cb[(r*8+((  q)^(r&7)))*8];
      bf16x8 xl=*(const bf16x8*)&cb[(r*8+((4+q)^(r&7)))*8];
      ac[i]=MF(c2h[i],xh,ac[i]); ac[i]=MF(c2h[i],xl,ac[i]); ac[i]=MF(c2l[i],xh,ac[i]);
    }
    __builtin_amdgcn_s_setprio(0);
  }
  // ---- prefetch exp1 kc=0 weights (overlaps gate) ----
  const unsigned short* e1wh=Whi+49152; const unsigned short* e1wl=Wlo+49152;
  int ob1 = wid*32;
  bf16x8 p1h[2], p1l[2];
  #pragma unroll
  for(int mt=0;mt<2;mt++){
    size_t wo=(size_t)(ob1+mt*16+l15)*192 + q*8;
    p1h[mt]=*(const bf16x8*)(e1wh+wo); p1l[mt]=*(const bf16x8*)(e1wl+wo);
  }
  // ---- gate (vectorized RMW) ----
  #pragma unroll
  for(int i=0;i<6;i++){
    int j=wid*6+i, ot=j>>2, nf=j&3, n=nf*16+l15;
    int c0=ot*16+q*4;
    float4 cb4 = *(const float4*)&c2bias[c0];
    float xv[4];
    get_split4(buf, n, c0, xv);
    xv[0] *= 1.f/(1.f+__expf(-(ac[i][0]+cb4.x)));
    xv[1] *= 1.f/(1.f+__expf(-(ac[i][1]+cb4.y)));
    xv[2] *= 1.f/(1.f+__expf(-(ac[i][2]+cb4.z)));
    xv[3] *= 1.f/(1.f+__expf(-(ac[i][3]+cb4.w)));
    put_split4(buf, n, c0, xv);
  }
  __syncthreads();
  // ---- exp1: out 256, K=192; regs accumulate, then overwrite buf ----
  {
    f32x4 e1a[2][4];
    #pragma unroll
    for(int a=0;a<2;a++)
      #pragma unroll
      for(int d=0;d<4;d++) e1a[a][d]=(f32x4){0.f,0.f,0.f,0.f};
    __builtin_amdgcn_s_setprio(1);
    #pragma unroll
    for(int kc=0;kc<6;kc++){
      bf16x8 nh[2], nl[2];
      if(kc<5){
        #pragma unroll
        for(int mt=0;mt<2;mt++){
          size_t wo=(size_t)(ob1+mt*16+l15)*192 + (kc+1)*32 + q*8;
          nh[mt]=*(const bf16x8*)(e1wh+wo); nl[mt]=*(const bf16x8*)(e1wl+wo);
        }
      }
      const unsigned short* cb = buf + kc*4096;
      #pragma unroll
      for(int nf=0;nf<4;nf++){
        int r=nf*16+l15;
        bf16x8 xh=*(const bf16x8*)&cb[(r*8+((  q)^(r&7)))*8];
        bf16x8 xl=*(const bf16x8*)&cb[(r*8+((4+q)^(r&7)))*8];
        e1a[0][nf]=MF(p1h[0],xh,e1a[0][nf]); e1a[1][nf]=MF(p1h[1],xh,e1a[1][nf]);
        e1a[0][nf]=MF(p1h[0],xl,e1a[0][nf]); e1a[1][nf]=MF(p1h[1],xl,e1a[1][nf]);
        e1a[0][nf]=MF(p1l[0],xh,e1a[0][nf]); e1a[1][nf]=MF(p1l[1],xh,e1a[1][nf]);
      }
      p1h[0]=nh[0]; p1h[1]=nh[1]; p1l[0]=nl[0]; p1l[1]=nl[1];
    }
    __builtin_amdgcn_s_setprio(0);
    __syncthreads();   // all reads of X retired; buf is now free
    // prefetch exp2 kc=0 weights (overlaps exp1 epilogue + barrier)
    const unsigned short* e2wh=Whi+98304; const unsigned short* e2wl=Wlo+98304;
    int ob2 = wid*64;
    bf16x8 p2h[4], p2l[4];
    #pragma unroll
    for(int mt=0;mt<4;mt++){
      size_t wo=(size_t)(ob2+mt*16+l15)*256 + q*8;
      p2h[mt]=*(const bf16x8*)(e2wh+wo); p2l[mt]=*(const bf16x8*)(e2wl+wo);
    }
    // exp1 epilogue (vectorized)
    #pragma unroll
    for(int mt=0;mt<2;mt++){
      int c0 = ob1+mt*16+q*4;
      float4 sg = *(const float4*)&e1g[c0];
      float4 bb = *(const float4*)&e1b[c0];
      #pragma unroll
      for(int nf=0;nf<4;nf++){
        float v[4];
        v[0]=fmaxf(e1a[mt][nf][0]*sg.x*BNS+bb.x,0.f);
        v[1]=fmaxf(e1a[mt][nf][1]*sg.y*BNS+bb.y,0.f);
        v[2]=fmaxf(e1a[mt][nf][2]*sg.z*BNS+bb.z,0.f);
        v[3]=fmaxf(e1a[mt][nf][3]*sg.w*BNS+bb.w,0.f);
        put_split4(buf, nf*16+l15, c0, v);
      }
    }
    __syncthreads();
    // ---- exp2: out 512, K=256; bn -> max-pool over 64 rows ----
    f32x4 a2[4][4];
    #pragma unroll
    for(int a=0;a<4;a++)
      #pragma unroll
      for(int d=0;d<4;d++) a2[a][d]=(f32x4){0.f,0.f,0.f,0.f};
    {  // kc = 0 (prefetched weights)
      const unsigned short* cb = buf;
      __builtin_amdgcn_s_setprio(1);
      #pragma unroll
      for(int nf=0;nf<4;nf++){
        int r=nf*16+l15;
        bf16x8 xh=*(const bf16x8*)&cb[(r*8+((  q)^(r&7)))*8];
        bf16x8 xl=*(const bf16x8*)&cb[(r*8+((4+q)^(r&7)))*8];
        #pragma unroll
        for(int mt=0;mt<4;mt++) a2[mt][nf]=MF(p2h[mt],xh,a2[mt][nf]);
        #pragma unroll
        for(int mt=0;mt<4;mt++) a2[mt][nf]=MF(p2h[mt],xl,a2[mt][nf]);
        #pragma unroll
        for(int mt=0;mt<4;mt++) a2[mt][nf]=MF(p2l[mt],xh,a2[mt][nf]);
      }
      __builtin_amdgcn_s_setprio(0);
    }
    for(int kc=1;kc<8;kc++){
      bf16x8 ch[4], cl[4];
      #pragma unroll
      for(int mt=0;mt<4;mt++){
        size_t wo=(size_t)(ob2+mt*16+l15)*256 + kc*32 + q*8;
        ch[mt]=*(const bf16x8*)(e2wh+wo); cl[mt]=*(const bf16x8*)(e2wl+wo);
      }
      const unsigned short* cb = buf + kc*4096;
      __builtin_amdgcn_s_setprio(1);
      #pragma unroll
      for(int nf=0;nf<4;nf++){
        int r=nf*16+l15;
        bf16x8 xh=*(const bf16x8*)&cb[(r*8+((  q)^(r&7)))*8];
        bf16x8 xl=*(const bf16x8*)&cb[(r*8+((4+q)^(r&7)))*8];
        #pragma unroll
        for(int mt=0;mt<4;mt++) a2[mt][nf]=MF(ch[mt],xh,a2[mt][nf]);
        #pragma unroll
        for(int mt=0;mt<4;mt++) a2[mt][nf]=MF(ch[mt],xl,a2[mt][nf]);
      }
      #pragma unroll
      for(int nf=0;nf<4;nf++){
        int r=nf*16+l15;
        bf16x8 xh=*(const bf16x8*)&cb[(r*8+((  q)^(r&7)))*8];
        #pragma unroll
        for(int mt=0;mt<4;mt++) a2[mt][nf]=MF(cl[mt],xh,a2[mt][nf]);
      }
      __builtin_amdgcn_s_setprio(0);
    }
    int b = bm>>8, m = bm&255;
    #pragma unroll
    for(int mt=0;mt<4;mt++){
      int c0 = ob2+mt*16+q*4;
      float4 sg = *(const float4*)&e2g[c0];
      float4 bb = *(const float4*)&e2b[c0];
      float s[4]={sg.x*BNS,sg.y*BNS,sg.z*BNS,sg.w*BNS};
      float bbv[4]={bb.x,bb.y,bb.z,bb.w};
      #pragma unroll
      for(int rr=0;rr<4;rr++){
        float v = a2[mt][0][rr]*s[rr]+bbv[rr];
        v = fmaxf(v, a2[mt][1][rr]*s[rr]+bbv[rr]);
        v = fmaxf(v, a2[mt][2][rr]*s[rr]+bbv[rr]);
        v = fmaxf(v, a2[mt][3][rr]*s[rr]+bbv[rr]);
        v = fmaxf(v, 0.f);
        v = fmaxf(v, __shfl_xor(v,1));
        v = fmaxf(v, __shfl_xor(v,2));
        v = fmaxf(v, __shfl_xor(v,4));
        v = fmaxf(v, __shfl_xor(v,8));
        if(l15==0) pool[((size_t)b*512 + c0+rr)*256 + m] = v;
      }
    }
  }
}

// ------- fused head: red -> sc1 -> sc2, one block = (b, 2 cols) -------------
// 1024 threads: K-dim split across 4 quarters (h), LDS partial combine.
__global__ __launch_bounds__(1024) void k_headf(const float* __restrict__ Wt_red,
    const float* __restrict__ Wt_s1, const float* __restrict__ Wt_s2,
    const float* __restrict__ pool, float* __restrict__ Og,
    const float* __restrict__ red_g, const float* __restrict__ red_b,
    const float* __restrict__ n1g, const float* __restrict__ n1b,
    const float* __restrict__ s1b, const float* __restrict__ s2b,
    const float* __restrict__ n2g, const float* __restrict__ n2b){
  __shared__ float P[512*3];
  __shared__ float X1[256*3];
  __shared__ float H[256*3];
  __shared__ float PB[256*9];
  int g = blockIdx.x;
  int b = g>>7, mg = g&127;
  int m0 = mg*2;
  int tid = threadIdx.x;
  int o = tid&255, h = tid>>8;   // h in 0..3
  if(tid<512){
    int c = tid;
    float2 v = *(const float2*)&pool[((size_t)b*512+c)*256 + m0];
    P[c*3+0]=v.x; P[c*3+1]=v.y;
  }
  __syncthreads();
  float a0=0.f, a1=0.f;
  // red: K=512, quarter per h
  {
    int c0 = h*128;
    #pragma unroll 8
    for(int i=0;i<128;i++){
      int c = c0+i;
      float w = Wt_red[c*256+o];
      a0 += w*P[c*3]; a1 += w*P[c*3+1];
    }
  }
  PB[o*9+h*2]=a0; PB[o*9+h*2+1]=a1;
  __syncthreads();
  a0 = (PB[o*9+0]+PB[o*9+2])+(PB[o*9+4]+PB[o*9+6]);
  a1 = (PB[o*9+1]+PB[o*9+3])+(PB[o*9+5]+PB[o*9+7]);
  float x0r,x1r;
  {
    float s=red_g[o]*BNS, bi=red_b[o], s1=n1g[o]*BNS, b1=n1b[o];
    float r0=fmaxf(a0*s+bi,0.f), r1=fmaxf(a1*s+bi,0.f);
    x0r=2.f*r0*s1+b1; x1r=2.f*r1*s1+b1;
    if(h==0){ X1[o*3]=x0r; X1[o*3+1]=x1r; }
  }
  __syncthreads();
  // sc1: K=256, quarters of 64
  a0=0.f; a1=0.f;
  {
    int c0 = h*64;
    #pragma unroll 8
    for(int i=0;i<64;i++){
      int c = c0+i;
      float w = Wt_s1[c*256+o];
      a0 += w*X1[c*3]; a1 += w*X1[c*3+1];
    }
  }
  PB[o*9+h*2]=a0; PB[o*9+h*2+1]=a1;
  __syncthreads();
  a0 = (PB[o*9+0]+PB[o*9+2])+(PB[o*9+4]+PB[o*9+6]);
  a1 = (PB[o*9+1]+PB[o*9+3])+(PB[o*9+5]+PB[o*9+7]);
  {
    float bi=s1b[o];
    if(h==0){ H[o*3]=fmaxf(a0+bi,0.f); H[o*3+1]=fmaxf(a1+bi,0.f); }
  }
  __syncthreads();
  // sc2 + residual + bn2
  a0=0.f; a1=0.f;
  {
    int c0 = h*64;
    #pragma unroll 8
    for(int i=0;i<64;i++){
      int c = c0+i;
      float w = Wt_s2[c*256+o];
      a0 += w*H[c*3]; a1 += w*H[c*3+1];
    }
  }
  PB[o*9+h*2]=a0; PB[o*9+h*2+1]=a1;
  __syncthreads();
  if(h==0){
    a0 = (PB[o*9+0]+PB[o*9+2])+(PB[o*9+4]+PB[o*9+6]);
    a1 = (PB[o*9+1]+PB[o*9+3])+(PB[o*9+5]+PB[o*9+7]);
    float bi=s2b[o], s2=n2g[o]*BNS, b2=n2b[o];
    float v0=(x0r+a0+bi)*s2+b2, v1=(x1r+a1+bi)*s2+b2;
    *(float2*)&Og[((size_t)b*256+o)*256 + m0] = make_float2(v0,v1);
  }
}

extern "C" void kernel_launch(void* const* d_in, const int* in_sizes, int n_in,
                              void* d_out, int out_size, void* d_ws, size_t ws_size,
                              hipStream_t stream){
  const float* xyz     =(const float*)d_in[0];
  const float* feats   =(const float*)d_in[1];
  const float* e1_w    =(const float*)d_in[2];
  const float* e1_g    =(const float*)d_in[3];
  const float* e1_b    =(const float*)d_in[4];
  const float* e2_w    =(const float*)d_in[5];
  const float* e2_g    =(const float*)d_in[6];
  const float* e2_b    =(const float*)d_in[7];
  const float* cal1_w  =(const float*)d_in[8];
  const float* cal1_g  =(const float*)d_in[9];
  const float* cal1_b  =(const float*)d_in[10];
  const float* cal2_w  =(const float*)d_in[11];
  const float* cal2_bias=(const float*)d_in[12];
  const float* exp1_w  =(const float*)d_in[13];
  const float* exp1_g  =(const float*)d_in[14];
  const float* exp1_b  =(const float*)d_in[15];
  const float* exp2_w  =(const float*)d_in[16];
  const float* exp2_g  =(const float*)d_in[17];
  const float* exp2_b  =(const float*)d_in[18];
  const float* red_w   =(const float*)d_in[19];
  const float* red_g   =(const float*)d_in[20];
  const float* red_b   =(const float*)d_in[21];
  const float* sc1_w   =(const float*)d_in[22];
  const float* sc1_b   =(const float*)d_in[23];
  const float* sc2_w   =(const float*)d_in[24];
  const float* sc2_b   =(const float*)d_in[25];
  const float* sc_n1_g =(const float*)d_in[26];
  const float* sc_n1_b =(const float*)d_in[27];
  const float* sc_n2_g =(const float*)d_in[28];
  const float* sc_n2_b =(const float*)d_in[29];

  char* wsb=(char*)d_ws;
  unsigned short* cats=(unsigned short*)(wsb + 10485760);         // 24 MB [row][2][192]
  float*          pool=(float*)         (wsb + 69206016);         // 1 MB
  unsigned short* Whi =(unsigned short*)(wsb + 75497472);         // 448 KB
  unsigned short* Wlo =(unsigned short*)(wsb + 76021760);         // 448 KB
  float*          Wt_red=(float*)       (wsb + 76546048);         // 512 KB
  float*          Wt_s1 =(float*)       (wsb + 77070336);         // 256 KB
  float*          Wt_s2 =(float*)       (wsb + 77332480);         // 256 KB
  unsigned short* e1e_h=Whi;          unsigned short* e1e_l=Wlo;          // 128x64
  unsigned short* e2e_h=Whi+8192;     unsigned short* e2e_l=Wlo+8192;     // 256x64

  k_prep      <<<1152,256,0,stream>>>(e1_w,e2_w,cal1_w,cal2_w,exp1_w,exp2_w,Whi,Wlo,
                                      red_w,sc1_w,sc2_w,Wt_red,Wt_s1,Wt_s2);
  k_knne12    <<<512,512,0,stream>>>(xyz,feats,e1e_h,e1e_l,e2e_h,e2e_l,
                                     e1_g,e1_b,e2_g,e2_b,cats);
  k_mlp       <<<512,512,0,stream>>>(Whi,Wlo,cats,cal1_g,cal1_b,cal2_bias,
                                     exp1_g,exp1_b,exp2_g,exp2_b,pool);
  k_headf     <<<256,1024,0,stream>>>(Wt_red,Wt_s1,Wt_s2,pool,(float*)d_out,
                                      red_g,red_b,sc_n1_g,sc_n1_b,sc1_b,sc2_b,sc_n2_g,sc_n2_b);
}

// Round 11
// 236.890 us; speedup vs baseline: 1.0364x; 1.0022x over previous
//
#include <hip/hip_runtime.h>
#include <hip/hip_bf16.h>
#include <math.h>
#include <stddef.h>

#define DEV __device__ __forceinline__
__device__ const float BNS = 0.99999500003749968f; // 1/sqrt(1+1e-5)

typedef __bf16 bf16x8 __attribute__((ext_vector_type(8)));
typedef float  f32x4  __attribute__((ext_vector_type(4)));

#define MF(a,b,c) __builtin_amdgcn_mfma_f32_16x16x32_bf16(a,b,c,0,0,0)

DEV unsigned short f2bs(float v){
  union{ __hip_bfloat16 b; unsigned short u; } c; c.b=__float2bfloat16(v); return c.u;
}
DEV float bs2f(unsigned short u){
  union{ unsigned short u; __hip_bfloat16 b; } c; c.u=u; return __bfloat162float(c.b);
}

// Chunked split-bf16 LDS layout: chunk cc covers channels [cc*32, cc*32+32),
// 64 rows x 64 ushorts (32 hi + 32 lo), XOR-swizzled like the GEMM staging:
// unit up = u ^ (row&7), u<4 = hi k-offset u*8, u>=4 = lo.
// Channel quads c0..c0+3 (c0 % 4 == 0) are CONTIGUOUS ushorts -> vector ops.
DEV void put_split4(unsigned short* chunks, int n, int c0, const float* v){
  int cc=c0>>5, u=(c0>>3)&3, e=c0&7;          // e in {0,4}
  unsigned short* base = chunks + cc*4096;
  unsigned short h0=f2bs(v[0]), h1=f2bs(v[1]), h2=f2bs(v[2]), h3=f2bs(v[3]);
  ushort4 hq = make_ushort4(h0,h1,h2,h3);
  ushort4 lq = make_ushort4(f2bs(v[0]-bs2f(h0)), f2bs(v[1]-bs2f(h1)),
                            f2bs(v[2]-bs2f(h2)), f2bs(v[3]-bs2f(h3)));
  *(ushort4*)&base[(n*8 + (u     ^ (n&7)))*8 + e] = hq;
  *(ushort4*)&base[(n*8 + ((u+4) ^ (n&7)))*8 + e] = lq;
}
DEV void get_split4(const unsigned short* chunks, int n, int c0, float* v){
  int cc=c0>>5, u=(c0>>3)&3, e=c0&7;
  const unsigned short* base = chunks + cc*4096;
  ushort4 hq = *(const ushort4*)&base[(n*8 + (u     ^ (n&7)))*8 + e];
  ushort4 lq = *(const ushort4*)&base[(n*8 + ((u+4) ^ (n&7)))*8 + e];
  v[0]=bs2f(hq.x)+bs2f(lq.x); v[1]=bs2f(hq.y)+bs2f(lq.y);
  v[2]=bs2f(hq.z)+bs2f(lq.z); v[3]=bs2f(hq.w)+bs2f(lq.w);
}

// Geometry: B=2, M=256 -> 512 bm groups, N=64 pts, KNN=16, CIN=64,
// edge1 O=64, edge2 O=128, SUMM=192, CALIB=64, EXP=256/512, OUT=256. f32 I/O.
// Split-bf16 activation layout in cats: [row][2][192] ushort (hi, lo).

// ------- fused prep: 6 weight splits + 3 head transposes in one launch ------
// mode-0 sections coarsened 4x (4 elems/thread): grid 1152 -> 552.
__global__ __launch_bounds__(256) void k_prep(const float* __restrict__ e1_w,
    const float* __restrict__ e2_w, const float* __restrict__ cal1_w,
    const float* __restrict__ cal2_w, const float* __restrict__ exp1_w,
    const float* __restrict__ exp2_w, unsigned short* __restrict__ Whi,
    unsigned short* __restrict__ Wlo,
    const float* __restrict__ red_w, const float* __restrict__ sc1_w,
    const float* __restrict__ sc2_w, float* __restrict__ Wt_red,
    float* __restrict__ Wt_s1, float* __restrict__ Wt_s2){
  __shared__ float s[32][33];
  int bid = blockIdx.x;
  if(bid < 96){          // edge weights (mode 1), 1 elem/thread
    const float* src; unsigned short *hi,*lo; int O, i0;
    if(bid<32){ src=e1_w; hi=Whi;      lo=Wlo;      O= 64; i0=bid*256; }
    else      { src=e2_w; hi=Whi+8192; lo=Wlo+8192; O=128; i0=(bid-32)*256; }
    int i = i0 + threadIdx.x;
    int row=i>>6, c=i&63;
    float v = (row<O) ? src[row*128+c] : (src[(row-O)*128+64+c]-src[(row-O)*128+c]);
    unsigned short h=f2bs(v); hi[i]=h; lo[i]=f2bs(v-bs2f(h));
  } else if(bid < 296){  // plain splits (mode 0), 4 elems/thread
    const float* src; unsigned short *hi,*lo; int i0;
    if(bid<108)      { src=cal1_w; hi=Whi+24576; lo=Wlo+24576; i0=(bid-96)*1024; }
    else if(bid<120) { src=cal2_w; hi=Whi+36864; lo=Wlo+36864; i0=(bid-108)*1024; }
    else if(bid<168) { src=exp1_w; hi=Whi+49152; lo=Wlo+49152; i0=(bid-120)*1024; }
    else             { src=exp2_w; hi=Whi+98304; lo=Wlo+98304; i0=(bid-168)*1024; }
    #pragma unroll
    for(int p=0;p<4;p++){
      int i = i0 + p*256 + threadIdx.x;
      float v = src[i];
      unsigned short h=f2bs(v); hi[i]=h; lo[i]=f2bs(v-bs2f(h));
    }
  } else {               // head transposes
    int lb = bid-296;
    const float* in; float* out; int O,K;
    if(lb<128){ in=red_w; out=Wt_red; O=256; K=512; }
    else if(lb<192){ in=sc1_w; out=Wt_s1; O=256; K=256; lb-=128; }
    else { in=sc2_w; out=Wt_s2; O=256; K=256; lb-=192; }
    int nt=O>>5;
    int to=lb%nt, tk=lb/nt;
    int c=threadIdx.x&31, r8=threadIdx.x>>5;
    #pragma unroll
    for(int p=0;p<4;p++){
      int r=r8+p*8;
      s[r][c]=in[(size_t)(to*32+r)*K + tk*32 + c];
    }
    __syncthreads();
    #pragma unroll
    for(int p=0;p<4;p++){
      int r=r8+p*8;
      out[(size_t)(tk*32+r)*O + to*32 + c]=s[c][r];
    }
  }
}

// -------- fused knn + edge1 + edge2: per bm, all in LDS ---------------------
// 512 threads / 8 waves; 56 KB LDS -> 2 blocks/CU.
// T14 async-STAGE: feats loads issue into regs BEFORE the top-16 phase (its
// ~1000cy VALU/shfl chain hides the L2/HBM latency); LDS writes in phase 2.
__global__ __launch_bounds__(512) void k_knne12(const float* __restrict__ xyz,
    const float* __restrict__ feats,
    const unsigned short* __restrict__ W1h, const unsigned short* __restrict__ W1l,
    const unsigned short* __restrict__ W2h, const unsigned short* __restrict__ W2l,
    const float* __restrict__ g1, const float* __restrict__ b1,
    const float* __restrict__ g2, const float* __restrict__ b2,
    unsigned short* __restrict__ cat){
  __shared__ float bufA[64*65];   // zs [ch][pt]
  __shared__ float bufB[64*65];   // ds [ch][pt]
  __shared__ __align__(16) unsigned short sb[64*136]; // x split -> e1out split
  __shared__ int   ips[64*16];
  __shared__ float sx0[64], sx1[64], sx2[64], sxx[64];
  int bm = blockIdx.x;
  int tid = threadIdx.x, n = tid&63, s = tid>>6;
  int wid = tid>>6, lane = tid&63;
  int l15 = lane&15, q = lane>>4;
  // ---- issue feats loads early (latency hidden under phase 1) ----
  const float* fb = feats + (size_t)bm*3904;   // 64*61
  float fv[8];
  #pragma unroll
  for(int i=0;i<8;i++){
    int idx = tid + i*512;
    fv[i] = (idx<3904) ? fb[idx] : 0.f;
  }
  if(s==0){
    const float* xp = xyz + (size_t)(bm*64+n)*3;
    float px=xp[0], py=xp[1], pz=xp[2];
    sx0[n]=px; sx1[n]=py; sx2[n]=pz; sxx[n]=px*px+py*py+pz*pz;
  }
  __syncthreads();
  // ---- phase 1: top-16 (8 waves x 8 points; 8 lanes/point x 8 candidates) --
  {
    int p = lane>>3, seg = lane&7;
    int n1 = wid*8 + p;
    float px=sx0[n1], py=sx1[n1], pz=sx2[n1], xxn=sxx[n1];
    float pdr[8];
    #pragma unroll
    for(int t=0;t<8;t++){
      int m = seg*8+t;
      pdr[t] = 2.f*(px*sx0[m]+py*sx1[m]+pz*sx2[m]) - xxn - sxx[m];
    }
    for(int j=0;j<16;j++){
      float bv=-3.4e38f; int bi=seg*8;
      #pragma unroll
      for(int t=0;t<8;t++){ if(pdr[t]>bv){bv=pdr[t]; bi=seg*8+t;} }  // strict >: lowest idx
      float ov; int oi;
      ov=__shfl_xor(bv,1); oi=__shfl_xor(bi,1);
      if(ov>bv || (ov==bv && oi<bi)){bv=ov;bi=oi;}
      ov=__shfl_xor(bv,2); oi=__shfl_xor(bi,2);
      if(ov>bv || (ov==bv && oi<bi)){bv=ov;bi=oi;}
      ov=__shfl_xor(bv,4); oi=__shfl_xor(bi,4);
      if(ov>bv || (ov==bv && oi<bi)){bv=ov;bi=oi;}
      if(seg==0) ips[n1*16+j]=bi;
      if((bi>>3)==seg) pdr[bi&7]=-3.4e38f;
    }
  }
  // ---- phase 2: split x into sb (regs -> LDS; loads already landed) ----
  {
    if(s==0){
      unsigned short* r = sb + n*136;
      float px=sx0[n], py=sx1[n], pz=sx2[n];
      unsigned short h;
      h=f2bs(px); r[0]=h; r[64]=f2bs(px-bs2f(h));
      h=f2bs(py); r[1]=h; r[65]=f2bs(py-bs2f(h));
      h=f2bs(pz); r[2]=h; r[66]=f2bs(pz-bs2f(h));
    }
    #pragma unroll
    for(int i=0;i<8;i++){
      int idx = tid + i*512;
      if(idx<3904){
        float v = fv[i];
        int row = idx/61, cc = idx - row*61;
        unsigned short h=f2bs(v);
        sb[row*136 + 3+cc]      = h;
        sb[row*136 + 64 + 3+cc] = f2bs(v-bs2f(h));
      }
    }
  }
  __syncthreads();
  // ---- phase 3: edge1 MFMA (8 waves x 16 weight-rows) ----
  {
    int rbase = wid*16;
    f32x4 acc[4];
    #pragma unroll
    for(int d=0;d<4;d++) acc[d]=(f32x4){0.f,0.f,0.f,0.f};
    #pragma unroll
    for(int kc=0;kc<2;kc++){
      int k0=kc*32;
      size_t a0=(size_t)(rbase+l15)*64 + k0 + q*8;
      bf16x8 a0h=*(const bf16x8*)(W1h+a0), a0l=*(const bf16x8*)(W1l+a0);
      #pragma unroll
      for(int nt=0;nt<4;nt++){
        int row = nt*16 + l15;
        bf16x8 bh = *(const bf16x8*)&sb[row*136 + k0 + q*8];
        bf16x8 bl = *(const bf16x8*)&sb[row*136 + 64 + k0 + q*8];
        acc[nt]=MF(a0h,bh,acc[nt]);
        acc[nt]=MF(a0h,bl,acc[nt]);
        acc[nt]=MF(a0l,bh,acc[nt]);
      }
    }
    __syncthreads();
    float* dst = (wid<4)? bufA : bufB;
    int ro = (wid&3)*16;
    #pragma unroll
    for(int nt=0;nt<4;nt++)
      #pragma unroll
      for(int rr=0;rr<4;rr++)
        dst[(ro+q*4+rr)*65 + nt*16+l15] = acc[nt][rr];
  }
  __syncthreads();
  // ---- phase 4: gather edge1; write cats[0:64) + e1out split into sb ----
  {
    int o = lane;
    float sc = g1[o]*BNS, bi = b1[o];
    #pragma unroll 4
    for(int j=0;j<8;j++){
      int nn = wid*8 + j;
      const int* ip = &ips[nn*16];
      float mz = -3.4e38f;
      #pragma unroll
      for(int k=0;k<16;k++) mz = fmaxf(mz, bufA[o*65 + ip[k]]);
      float v = fmaxf(sc*(mz + bufB[o*65 + nn]) + bi, 0.f);
      unsigned short hv = f2bs(v), lv = f2bs(v - bs2f(hv));
      size_t cb = ((size_t)bm*64+nn)*384 + o;
      cat[cb] = hv; cat[cb+192] = lv;
      sb[nn*136 + o] = hv; sb[nn*136 + 64 + o] = lv;  // x dead after phase 3
    }
  }
  // ---- phase 5: edge2 (2 chunks of 64 o) from sb ----
  for(int ch=0; ch<2; ch++){
    __syncthreads();
    int wrow = ((wid<4)?0:128) + ch*64 + (wid&3)*16;
    f32x4 acc[4];
    #pragma unroll
    for(int d=0;d<4;d++) acc[d]=(f32x4){0.f,0.f,0.f,0.f};
    #pragma unroll
    for(int kc=0;kc<2;kc++){
      int k0=kc*32;
      size_t a0=(size_t)(wrow+l15)*64 + k0 + q*8;
      bf16x8 a0h=*(const bf16x8*)(W2h+a0), a0l=*(const bf16x8*)(W2l+a0);
      #pragma unroll
      for(int nt=0;nt<4;nt++){
        int row = nt*16 + l15;
        bf16x8 bh = *(const bf16x8*)&sb[row*136 + k0 + q*8];
        bf16x8 bl = *(const bf16x8*)&sb[row*136 + 64 + k0 + q*8];
        acc[nt]=MF(a0h,bh,acc[nt]);
        acc[nt]=MF(a0h,bl,acc[nt]);
        acc[nt]=MF(a0l,bh,acc[nt]);
      }
    }
    __syncthreads();
    float* dst = (wid<4)? bufA : bufB;
    int ro = (wid&3)*16;
    #pragma unroll
    for(int nt=0;nt<4;nt++)
      #pragma unroll
      for(int rr=0;rr<4;rr++)
        dst[(ro+q*4+rr)*65 + nt*16+l15] = acc[nt][rr];
    __syncthreads();
    int o = ch*64 + lane;
    float sc = g2[o]*BNS, bi = b2[o];
    #pragma unroll 4
    for(int j=0;j<8;j++){
      int nn = wid*8 + j;
      const int* ip = &ips[nn*16];
      float mz = -3.4e38f;
      #pragma unroll
      for(int k=0;k<16;k++) mz = fmaxf(mz, bufA[lane*65 + ip[k]]);
      float v = fmaxf(sc*(mz + bufB[lane*65 + nn]) + bi, 0.f);
      unsigned short hv = f2bs(v);
      size_t cb = ((size_t)bm*64+nn)*384 + 64 + o;
      cat[cb] = hv; cat[cb+192] = f2bs(v - bs2f(hv));
    }
  }
}

// ------- fused MLP: cal1 -> cal2 -> gate -> exp1 -> exp2 -> pool ------------
// One block per bm group (64 rows), 512 threads. LDS overlay = 80 KB
// (2 blocks/CU). Round-5 structure; this round: setprio REMOVED (A/B per
// m190: setprio measured harmful on lockstep barrier-synced GEMM).
__global__ __launch_bounds__(512,4) void k_mlp(
    const unsigned short* __restrict__ Whi, const unsigned short* __restrict__ Wlo,
    const unsigned short* __restrict__ cats,
    const float* __restrict__ c1g, const float* __restrict__ c1b,
    const float* __restrict__ c2bias,
    const float* __restrict__ e1g, const float* __restrict__ e1b,
    const float* __restrict__ e2g, const float* __restrict__ e2b,
    float* __restrict__ pool){
  __shared__ __align__(16) unsigned short buf[8*4096];
  __shared__ __align__(16) unsigned short calB[2*4096];
  int bm = blockIdx.x;
  int tid = threadIdx.x, wid = tid>>6, lane = tid&63;
  int l15 = lane&15, q = lane>>4;

  // ---- issue cal1 kc=0 weight loads before staging (hide behind barrier) --
  const unsigned short* w1h = Whi + 24576;
  const unsigned short* w1l = Wlo + 24576;
  int c1ot = wid>>1, c1rh = wid&1;
  size_t c1wo0 = (size_t)(c1ot*16+l15)*192 + q*8;
  bf16x8 cah = *(const bf16x8*)(w1h+c1wo0);
  bf16x8 cal_ = *(const bf16x8*)(w1l+c1wo0);

  // ---- stage X (split, chunked+swizzled) into buf[0..5] ----
  size_t xb = (size_t)bm*24576;  // 64*384
  #pragma unroll
  for(int i=0;i<6;i++){
    int U = tid + i*512;
    int kc = U>>9, w = U&511, rr = w>>3, up = w&7, u = up ^ (rr&7);
    const unsigned short* src = cats + xb + (size_t)rr*384
      + (u<4 ? (kc*32 + u*8) : (192 + kc*32 + (u-4)*8));
    *(uint4*)&buf[kc*4096 + w*8] = *(const uint4*)src;
  }
  __syncthreads();

  // ---- cal1: out 64, K=192 -> calB; weight rotation ----
  f32x4 a0={0.f,0.f,0.f,0.f}, a1={0.f,0.f,0.f,0.f};
  {
    int r0 = c1rh*32+l15, r1 = c1rh*32+16+l15;
    #pragma unroll
    for(int kc=0;kc<6;kc++){
      bf16x8 nah, nal;
      if(kc<5){
        size_t wo = c1wo0 + (kc+1)*32;
        nah=*(const bf16x8*)(w1h+wo); nal=*(const bf16x8*)(w1l+wo);
      }
      const unsigned short* cb = buf + kc*4096;
      bf16x8 xh0=*(const bf16x8*)&cb[(r0*8+((  q)^(r0&7)))*8];
      bf16x8 xl0=*(const bf16x8*)&cb[(r0*8+((4+q)^(r0&7)))*8];
      bf16x8 xh1=*(const bf16x8*)&cb[(r1*8+((  q)^(r1&7)))*8];
      bf16x8 xl1=*(const bf16x8*)&cb[(r1*8+((4+q)^(r1&7)))*8];
      a0=MF(cah,xh0,a0); a1=MF(cah,xh1,a1);
      a0=MF(cah,xl0,a0); a1=MF(cah,xl1,a1);
      a0=MF(cal_,xh0,a0); a1=MF(cal_,xh1,a1);
      cah=nah; cal_=nal;
    }
  }
  // ---- prefetch cal2 kc=0 weights (overlaps cal1 epilogue + barrier) ----
  const unsigned short* w2h = Whi + 36864;
  const unsigned short* w2l = Wlo + 36864;
  bf16x8 c2h[6], c2l[6];
  #pragma unroll
  for(int i=0;i<6;i++){
    int ot = (wid*6+i)>>2;
    size_t wo=(size_t)(ot*16+l15)*64 + q*8;
    c2h[i]=*(const bf16x8*)(w2h+wo); c2l[i]=*(const bf16x8*)(w2l+wo);
  }
  // ---- cal1 epilogue (vectorized) ----
  {
    int c0 = c1ot*16+q*4;
    float4 sg = *(const float4*)&c1g[c0];
    float4 bb = *(const float4*)&c1b[c0];
    float v0[4], v1[4];
    v0[0]=fmaxf(a0[0]*sg.x*BNS+bb.x,0.f); v1[0]=fmaxf(a1[0]*sg.x*BNS+bb.x,0.f);
    v0[1]=fmaxf(a0[1]*sg.y*BNS+bb.y,0.f); v1[1]=fmaxf(a1[1]*sg.y*BNS+bb.y,0.f);
    v0[2]=fmaxf(a0[2]*sg.z*BNS+bb.z,0.f); v1[2]=fmaxf(a1[2]*sg.z*BNS+bb.z,0.f);
    v0[3]=fmaxf(a0[3]*sg.w*BNS+bb.w,0.f); v1[3]=fmaxf(a1[3]*sg.w*BNS+bb.w,0.f);
    put_split4(calB, c1rh*32+l15,    c0, v0);
    put_split4(calB, c1rh*32+16+l15, c0, v1);
  }
  __syncthreads();
  // ---- cal2: out 192, K=64 (calB); then sigmoid gate -> buf in place ----
  f32x4 ac[6];
  #pragma unroll
  for(int i=0;i<6;i++) ac[i]=(f32x4){0.f,0.f,0.f,0.f};
  #pragma unroll
  for(int kc=0;kc<2;kc++){
    const unsigned short* cb = calB + kc*4096;
    if(kc==1){
      #pragma unroll
      for(int i=0;i<6;i++){
        int ot = (wid*6+i)>>2;
        size_t wo=(size_t)(ot*16+l15)*64 + 32 + q*8;
        c2h[i]=*(const bf16x8*)(w2h+wo); c2l[i]=*(const bf16x8*)(w2l+wo);
      }
    }
    #pragma unroll
    for(int i=0;i<6;i++){
      int nf=(wid*6+i)&3;
      int r=nf*16+l15;
      bf16x8 xh=*(const bf16x8*)&cb[(r*8+((  q)^(r&7)))*8];
      bf16x8 xl=*(const bf16x8*)&cb[(r*8+((4+q)^(r&7)))*8];
      ac[i]=MF(c2h[i],xh,ac[i]); ac[i]=MF(c2h[i],xl,ac[i]); ac[i]=MF(c2l[i],xh,ac[i]);
    }
  }
  // ---- prefetch exp1 kc=0 weights (overlaps gate) ----
  const unsigned short* e1wh=Whi+49152; const unsigned short* e1wl=Wlo+49152;
  int ob1 = wid*32;
  bf16x8 p1h[2], p1l[2];
  #pragma unroll
  for(int mt=0;mt<2;mt++){
    size_t wo=(size_t)(ob1+mt*16+l15)*192 + q*8;
    p1h[mt]=*(const bf16x8*)(e1wh+wo); p1l[mt]=*(const bf16x8*)(e1wl+wo);
  }
  // ---- gate (vectorized RMW) ----
  #pragma unroll
  for(int i=0;i<6;i++){
    int j=wid*6+i, ot=j>>2, nf=j&3, n=nf*16+l15;
    int c0=ot*16+q*4;
    float4 cb4 = *(const float4*)&c2bias[c0];
    float xv[4];
    get_split4(buf, n, c0, xv);
    xv[0] *= 1.f/(1.f+__expf(-(ac[i][0]+cb4.x)));
    xv[1] *= 1.f/(1.f+__expf(-(ac[i][1]+cb4.y)));
    xv[2] *= 1.f/(1.f+__expf(-(ac[i][2]+cb4.z)));
    xv[3] *= 1.f/(1.f+__expf(-(ac[i][3]+cb4.w)));
    put_split4(buf, n, c0, xv);
  }
  __syncthreads();
  // ---- exp1: out 256, K=192; regs accumulate, then overwrite buf ----
  {
    f32x4 e1a[2][4];
    #pragma unroll
    for(int a=0;a<2;a++)
      #pragma unroll
      for(int d=0;d<4;d++) e1a[a][d]=(f32x4){0.f,0.f,0.f,0.f};
    #pragma unroll
    for(int kc=0;kc<6;kc++){
      bf16x8 nh[2], nl[2];
      if(kc<5){
        #pragma unroll
        for(int mt=0;mt<2;mt++){
          size_t wo=(size_t)(ob1+mt*16+l15)*192 + (kc+1)*32 + q*8;
          nh[mt]=*(const bf16x8*)(e1wh+wo); nl[mt]=*(const bf16x8*)(e1wl+wo);
        }
      }
      const unsigned short* cb = buf + kc*4096;
      #pragma unroll
      for(int nf=0;nf<4;nf++){
        int r=nf*16+l15;
        bf16x8 xh=*(const bf16x8*)&cb[(r*8+((  q)^(r&7)))*8];
        bf16x8 xl=*(const bf16x8*)&cb[(r*8+((4+q)^(r&7)))*8];
        e1a[0][nf]=MF(p1h[0],xh,e1a[0][nf]); e1a[1][nf]=MF(p1h[1],xh,e1a[1][nf]);
        e1a[0][nf]=MF(p1h[0],xl,e1a[0][nf]); e1a[1][nf]=MF(p1h[1],xl,e1a[1][nf]);
        e1a[0][nf]=MF(p1l[0],xh,e1a[0][nf]); e1a[1][nf]=MF(p1l[1],xh,e1a[1][nf]);
      }
      p1h[0]=nh[0]; p1h[1]=nh[1]; p1l[0]=nl[0]; p1l[1]=nl[1];
    }
    __syncthreads();   // all reads of X retired; buf is now free
    // prefetch exp2 kc=0 weights (overlaps exp1 epilogue + barrier)
    const unsigned short* e2wh=Whi+98304; const unsigned short* e2wl=Wlo+98304;
    int ob2 = wid*64;
    bf16x8 p2h[4], p2l[4];
    #pragma unroll
    for(int mt=0;mt<4;mt++){
      size_t wo=(size_t)(ob2+mt*16+l15)*256 + q*8;
      p2h[mt]=*(const bf16x8*)(e2wh+wo); p2l[mt]=*(const bf16x8*)(e2wl+wo);
    }
    // exp1 epilogue (vectorized)
    #pragma unroll
    for(int mt=0;mt<2;mt++){
      int c0 = ob1+mt*16+q*4;
      float4 sg = *(const float4*)&e1g[c0];
      float4 bb = *(const float4*)&e1b[c0];
      #pragma unroll
      for(int nf=0;nf<4;nf++){
        float v[4];
        v[0]=fmaxf(e1a[mt][nf][0]*sg.x*BNS+bb.x,0.f);
        v[1]=fmaxf(e1a[mt][nf][1]*sg.y*BNS+bb.y,0.f);
        v[2]=fmaxf(e1a[mt][nf][2]*sg.z*BNS+bb.z,0.f);
        v[3]=fmaxf(e1a[mt][nf][3]*sg.w*BNS+bb.w,0.f);
        put_split4(buf, nf*16+l15, c0, v);
      }
    }
    __syncthreads();
    // ---- exp2: out 512, K=256; bn -> max-pool over 64 rows ----
    f32x4 a2[4][4];
    #pragma unroll
    for(int a=0;a<4;a++)
      #pragma unroll
      for(int d=0;d<4;d++) a2[a][d]=(f32x4){0.f,0.f,0.f,0.f};
    {  // kc = 0 (prefetched weights)
      const unsigned short* cb = buf;
      #pragma unroll
      for(int nf=0;nf<4;nf++){
        int r=nf*16+l15;
        bf16x8 xh=*(const bf16x8*)&cb[(r*8+((  q)^(r&7)))*8];
        bf16x8 xl=*(const bf16x8*)&cb[(r*8+((4+q)^(r&7)))*8];
        #pragma unroll
        for(int mt=0;mt<4;mt++) a2[mt][nf]=MF(p2h[mt],xh,a2[mt][nf]);
        #pragma unroll
        for(int mt=0;mt<4;mt++) a2[mt][nf]=MF(p2h[mt],xl,a2[mt][nf]);
        #pragma unroll
        for(int mt=0;mt<4;mt++) a2[mt][nf]=MF(p2l[mt],xh,a2[mt][nf]);
      }
    }
    for(int kc=1;kc<8;kc++){
      bf16x8 ch[4], cl[4];
      #pragma unroll
      for(int mt=0;mt<4;mt++){
        size_t wo=(size_t)(ob2+mt*16+l15)*256 + kc*32 + q*8;
        ch[mt]=*(const bf16x8*)(e2wh+wo); cl[mt]=*(const bf16x8*)(e2wl+wo);
      }
      const unsigned short* cb = buf + kc*4096;
      #pragma unroll
      for(int nf=0;nf<4;nf++){
        int r=nf*16+l15;
        bf16x8 xh=*(const bf16x8*)&cb[(r*8+((  q)^(r&7)))*8];
        bf16x8 xl=*(const bf16x8*)&cb[(r*8+((4+q)^(r&7)))*8];
        #pragma unroll
        for(int mt=0;mt<4;mt++) a2[mt][nf]=MF(ch[mt],xh,a2[mt][nf]);
        #pragma unroll
        for(int mt=0;mt<4;mt++) a2[mt][nf]=MF(ch[mt],xl,a2[mt][nf]);
      }
      #pragma unroll
      for(int nf=0;nf<4;nf++){
        int r=nf*16+l15;
        bf16x8 xh=*(const bf16x8*)&cb[(r*8+((  q)^(r&7)))*8];
        #pragma unroll
        for(int mt=0;mt<4;mt++) a2[mt][nf]=MF(cl[mt],xh,a2[mt][nf]);
      }
    }
    int b = bm>>8, m = bm&255;
    #pragma unroll
    for(int mt=0;mt<4;mt++){
      int c0 = ob2+mt*16+q*4;
      float4 sg = *(const float4*)&e2g[c0];
      float4 bb = *(const float4*)&e2b[c0];
      float s[4]={sg.x*BNS,sg.y*BNS,sg.z*BNS,sg.w*BNS};
      float bbv[4]={bb.x,bb.y,bb.z,bb.w};
      #pragma unroll
      for(int rr=0;rr<4;rr++){
        float v = a2[mt][0][rr]*s[rr]+bbv[rr];
        v = fmaxf(v, a2[mt][1][rr]*s[rr]+bbv[rr]);
        v = fmaxf(v, a2[mt][2][rr]*s[rr]+bbv[rr]);
        v = fmaxf(v, a2[mt][3][rr]*s[rr]+bbv[rr]);
        v = fmaxf(v, 0.f);
        v = fmaxf(v, __shfl_xor(v,1));
        v = fmaxf(v, __shfl_xor(v,2));
        v = fmaxf(v, __shfl_xor(v,4));
        v = fmaxf(v, __shfl_xor(v,8));
        if(l15==0) pool[((size_t)b*512 + c0+rr)*256 + m] = v;
      }
    }
  }
}

// ------- fused head: red -> sc1 -> sc2, one block = (b, 2 cols) -------------
// 1024 threads: K-dim split across 4 quarters (h), LDS partial combine.
__global__ __launch_bounds__(1024) void k_headf(const float* __restrict__ Wt_red,
    const float* __restrict__ Wt_s1, const float* __restrict__ Wt_s2,
    const float* __restrict__ pool, float* __restrict__ Og,
    const float* __restrict__ red_g, const float* __restrict__ red_b,
    const float* __restrict__ n1g, const float* __restrict__ n1b,
    const float* __restrict__ s1b, const float* __restrict__ s2b,
    const float* __restrict__ n2g, const float* __restrict__ n2b){
  __shared__ float P[512*3];
  __shared__ float X1[256*3];
  __shared__ float H[256*3];
  __shared__ float PB[256*9];
  int g = blockIdx.x;
  int b = g>>7, mg = g&127;
  int m0 = mg*2;
  int tid = threadIdx.x;
  int o = tid&255, h = tid>>8;   // h in 0..3
  if(tid<512){
    int c = tid;
    float2 v = *(const float2*)&pool[((size_t)b*512+c)*256 + m0];
    P[c*3+0]=v.x; P[c*3+1]=v.y;
  }
  __syncthreads();
  float a0=0.f, a1=0.f;
  // red: K=512, quarter per h
  {
    int c0 = h*128;
    #pragma unroll 8
    for(int i=0;i<128;i++){
      int c = c0+i;
      float w = Wt_red[c*256+o];
      a0 += w*P[c*3]; a1 += w*P[c*3+1];
    }
  }
  PB[o*9+h*2]=a0; PB[o*9+h*2+1]=a1;
  __syncthreads();
  a0 = (PB[o*9+0]+PB[o*9+2])+(PB[o*9+4]+PB[o*9+6]);
  a1 = (PB[o*9+1]+PB[o*9+3])+(PB[o*9+5]+PB[o*9+7]);
  float x0r,x1r;
  {
    float s=red_g[o]*BNS, bi=red_b[o], s1=n1g[o]*BNS, b1=n1b[o];
    float r0=fmaxf(a0*s+bi,0.f), r1=fmaxf(a1*s+bi,0.f);
    x0r=2.f*r0*s1+b1; x1r=2.f*r1*s1+b1;
    if(h==0){ X1[o*3]=x0r; X1[o*3+1]=x1r; }
  }
  __syncthreads();
  // sc1: K=256, quarters of 64
  a0=0.f; a1=0.f;
  {
    int c0 = h*64;
    #pragma unroll 8
    for(int i=0;i<64;i++){
      int c = c0+i;
      float w = Wt_s1[c*256+o];
      a0 += w*X1[c*3]; a1 += w*X1[c*3+1];
    }
  }
  PB[o*9+h*2]=a0; PB[o*9+h*2+1]=a1;
  __syncthreads();
  a0 = (PB[o*9+0]+PB[o*9+2])+(PB[o*9+4]+PB[o*9+6]);
  a1 = (PB[o*9+1]+PB[o*9+3])+(PB[o*9+5]+PB[o*9+7]);
  {
    float bi=s1b[o];
    if(h==0){ H[o*3]=fmaxf(a0+bi,0.f); H[o*3+1]=fmaxf(a1+bi,0.f); }
  }
  __syncthreads();
  // sc2 + residual + bn2
  a0=0.f; a1=0.f;
  {
    int c0 = h*64;
    #pragma unroll 8
    for(int i=0;i<64;i++){
      int c = c0+i;
      float w = Wt_s2[c*256+o];
      a0 += w*H[c*3]; a1 += w*H[c*3+1];
    }
  }
  PB[o*9+h*2]=a0; PB[o*9+h*2+1]=a1;
  __syncthreads();
  if(h==0){
    a0 = (PB[o*9+0]+PB[o*9+2])+(PB[o*9+4]+PB[o*9+6]);
    a1 = (PB[o*9+1]+PB[o*9+3])+(PB[o*9+5]+PB[o*9+7]);
    float bi=s2b[o], s2=n2g[o]*BNS, b2=n2b[o];
    float v0=(x0r+a0+bi)*s2+b2, v1=(x1r+a1+bi)*s2+b2;
    *(float2*)&Og[((size_t)b*256+o)*256 + m0] = make_float2(v0,v1);
  }
}

extern "C" void kernel_launch(void* const* d_in, const int* in_sizes, int n_in,
                              void* d_out, int out_size, void* d_ws, size_t ws_size,
                              hipStream_t stream){
  const float* xyz     =(const float*)d_in[0];
  const float* feats   =(const float*)d_in[1];
  const float* e1_w    =(const float*)d_in[2];
  const float* e1_g    =(const float*)d_in[3];
  const float* e1_b    =(const float*)d_in[4];
  const float* e2_w    =(const float*)d_in[5];
  const float* e2_g    =(const float*)d_in[6];
  const float* e2_b    =(const float*)d_in[7];
  const float* cal1_w  =(const float*)d_in[8];
  const float* cal1_g  =(const float*)d_in[9];
  const float* cal1_b  =(const float*)d_in[10];
  const float* cal2_w  =(const float*)d_in[11];
  const float* cal2_bias=(const float*)d_in[12];
  const float* exp1_w  =(const float*)d_in[13];
  const float* exp1_g  =(const float*)d_in[14];
  const float* exp1_b  =(const float*)d_in[15];
  const float* exp2_w  =(const float*)d_in[16];
  const float* exp2_g  =(const float*)d_in[17];
  const float* exp2_b  =(const float*)d_in[18];
  const float* red_w   =(const float*)d_in[19];
  const float* red_g   =(const float*)d_in[20];
  const float* red_b   =(const float*)d_in[21];
  const float* sc1_w   =(const float*)d_in[22];
  const float* sc1_b   =(const float*)d_in[23];
  const float* sc2_w   =(const float*)d_in[24];
  const float* sc2_b   =(const float*)d_in[25];
  const float* sc_n1_g =(const float*)d_in[26];
  const float* sc_n1_b =(const float*)d_in[27];
  const float* sc_n2_g =(const float*)d_in[28];
  const float* sc_n2_b =(const float*)d_in[29];

  char* wsb=(char*)d_ws;
  unsigned short* cats=(unsigned short*)(wsb + 10485760);         // 24 MB [row][2][192]
  float*          pool=(float*)         (wsb + 69206016);         // 1 MB
  unsigned short* Whi =(unsigned short*)(wsb + 75497472);         // 448 KB
  unsigned short* Wlo =(unsigned short*)(wsb + 76021760);         // 448 KB
  float*          Wt_red=(float*)       (wsb + 76546048);         // 512 KB
  float*          Wt_s1 =(float*)       (wsb + 77070336);         // 256 KB
  float*          Wt_s2 =(float*)       (wsb + 77332480);         // 256 KB
  unsigned short* e1e_h=Whi;          unsigned short* e1e_l=Wlo;          // 128x64
  unsigned short* e2e_h=Whi+8192;     unsigned short* e2e_l=Wlo+8192;     // 256x64

  k_prep      <<<552,256,0,stream>>>(e1_w,e2_w,cal1_w,cal2_w,exp1_w,exp2_w,Whi,Wlo,
                                     red_w,sc1_w,sc2_w,Wt_red,Wt_s1,Wt_s2);
  k_knne12    <<<512,512,0,stream>>>(xyz,feats,e1e_h,e1e_l,e2e_h,e2e_l,
                                     e1_g,e1_b,e2_g,e2_b,cats);
  k_mlp       <<<512,512,0,stream>>>(Whi,Wlo,cats,cal1_g,cal1_b,cal2_bias,
                                     exp1_g,exp1_b,exp2_g,exp2_b,pool);
  k_headf     <<<256,1024,0,stream>>>(Wt_red,Wt_s1,Wt_s2,pool,(float*)d_out,
                                      red_g,red_b,sc_n1_g,sc_n1_b,sc1_b,sc2_b,sc_n2_g,sc_n2_b);
}

// Round 12
// 236.120 us; speedup vs baseline: 1.0398x; 1.0033x over previous
//
#include <hip/hip_runtime.h>
#include <hip/hip_bf16.h>
#include <math.h>
#include <stddef.h>

#define DEV __device__ __forceinline__
__device__ const float BNS = 0.99999500003749968f; // 1/sqrt(1+1e-5)

typedef __bf16 bf16x8 __attribute__((ext_vector_type(8)));
typedef float  f32x4  __attribute__((ext_vector_type(4)));

#define MF(a,b,c) __builtin_amdgcn_mfma_f32_16x16x32_bf16(a,b,c,0,0,0)

DEV unsigned short f2bs(float v){
  union{ __hip_bfloat16 b; unsigned short u; } c; c.b=__float2bfloat16(v); return c.u;
}
DEV float bs2f(unsigned short u){
  union{ unsigned short u; __hip_bfloat16 b; } c; c.u=u; return __bfloat162float(c.b);
}

// Chunked split-bf16 LDS layout: chunk cc covers channels [cc*32, cc*32+32),
// 64 rows x 64 ushorts (32 hi + 32 lo), XOR-swizzled like the GEMM staging:
// unit up = u ^ (row&7), u<4 = hi k-offset u*8, u>=4 = lo.
// Channel quads c0..c0+3 (c0 % 4 == 0) are CONTIGUOUS ushorts -> vector ops.
DEV void put_split4(unsigned short* chunks, int n, int c0, const float* v){
  int cc=c0>>5, u=(c0>>3)&3, e=c0&7;          // e in {0,4}
  unsigned short* base = chunks + cc*4096;
  unsigned short h0=f2bs(v[0]), h1=f2bs(v[1]), h2=f2bs(v[2]), h3=f2bs(v[3]);
  ushort4 hq = make_ushort4(h0,h1,h2,h3);
  ushort4 lq = make_ushort4(f2bs(v[0]-bs2f(h0)), f2bs(v[1]-bs2f(h1)),
                            f2bs(v[2]-bs2f(h2)), f2bs(v[3]-bs2f(h3)));
  *(ushort4*)&base[(n*8 + (u     ^ (n&7)))*8 + e] = hq;
  *(ushort4*)&base[(n*8 + ((u+4) ^ (n&7)))*8 + e] = lq;
}
DEV void get_split4(const unsigned short* chunks, int n, int c0, float* v){
  int cc=c0>>5, u=(c0>>3)&3, e=c0&7;
  const unsigned short* base = chunks + cc*4096;
  ushort4 hq = *(const ushort4*)&base[(n*8 + (u     ^ (n&7)))*8 + e];
  ushort4 lq = *(const ushort4*)&base[(n*8 + ((u+4) ^ (n&7)))*8 + e];
  v[0]=bs2f(hq.x)+bs2f(lq.x); v[1]=bs2f(hq.y)+bs2f(lq.y);
  v[2]=bs2f(hq.z)+bs2f(lq.z); v[3]=bs2f(hq.w)+bs2f(lq.w);
}

// [pt][68-f32] buffer with XOR quad swizzle: float index of the quad holding
// channels 4*c4..4*c4+3 of point pt. Reads sweeping c4 per fixed pt are a
// permutation (conflict-free); stores with l15-varying pt get quad columns
// XOR-spread across banks (fixes the round-8 write serialization).
DEV int bidx(int pt, int c4){ return pt*68 + ((c4 ^ (pt&15))<<2); }

// Geometry: B=2, M=256 -> 512 bm groups, N=64 pts, KNN=16, CIN=64,
// edge1 O=64, edge2 O=128, SUMM=192, CALIB=64, EXP=256/512, OUT=256. f32 I/O.
// Split-bf16 activation layout in cats: [row][2][192] ushort (hi, lo).

// ------- fused prep: 6 weight splits + 3 head transposes in one launch ------
// mode-0 sections coarsened 4x (4 elems/thread): grid 1152 -> 552.
__global__ __launch_bounds__(256) void k_prep(const float* __restrict__ e1_w,
    const float* __restrict__ e2_w, const float* __restrict__ cal1_w,
    const float* __restrict__ cal2_w, const float* __restrict__ exp1_w,
    const float* __restrict__ exp2_w, unsigned short* __restrict__ Whi,
    unsigned short* __restrict__ Wlo,
    const float* __restrict__ red_w, const float* __restrict__ sc1_w,
    const float* __restrict__ sc2_w, float* __restrict__ Wt_red,
    float* __restrict__ Wt_s1, float* __restrict__ Wt_s2){
  __shared__ float s[32][33];
  int bid = blockIdx.x;
  if(bid < 96){          // edge weights (mode 1), 1 elem/thread
    const float* src; unsigned short *hi,*lo; int O, i0;
    if(bid<32){ src=e1_w; hi=Whi;      lo=Wlo;      O= 64; i0=bid*256; }
    else      { src=e2_w; hi=Whi+8192; lo=Wlo+8192; O=128; i0=(bid-32)*256; }
    int i = i0 + threadIdx.x;
    int row=i>>6, c=i&63;
    float v = (row<O) ? src[row*128+c] : (src[(row-O)*128+64+c]-src[(row-O)*128+c]);
    unsigned short h=f2bs(v); hi[i]=h; lo[i]=f2bs(v-bs2f(h));
  } else if(bid < 296){  // plain splits (mode 0), 4 elems/thread
    const float* src; unsigned short *hi,*lo; int i0;
    if(bid<108)      { src=cal1_w; hi=Whi+24576; lo=Wlo+24576; i0=(bid-96)*1024; }
    else if(bid<120) { src=cal2_w; hi=Whi+36864; lo=Wlo+36864; i0=(bid-108)*1024; }
    else if(bid<168) { src=exp1_w; hi=Whi+49152; lo=Wlo+49152; i0=(bid-120)*1024; }
    else             { src=exp2_w; hi=Whi+98304; lo=Wlo+98304; i0=(bid-168)*1024; }
    #pragma unroll
    for(int p=0;p<4;p++){
      int i = i0 + p*256 + threadIdx.x;
      float v = src[i];
      unsigned short h=f2bs(v); hi[i]=h; lo[i]=f2bs(v-bs2f(h));
    }
  } else {               // head transposes
    int lb = bid-296;
    const float* in; float* out; int O,K;
    if(lb<128){ in=red_w; out=Wt_red; O=256; K=512; }
    else if(lb<192){ in=sc1_w; out=Wt_s1; O=256; K=256; lb-=128; }
    else { in=sc2_w; out=Wt_s2; O=256; K=256; lb-=192; }
    int nt=O>>5;
    int to=lb%nt, tk=lb/nt;
    int c=threadIdx.x&31, r8=threadIdx.x>>5;
    #pragma unroll
    for(int p=0;p<4;p++){
      int r=r8+p*8;
      s[r][c]=in[(size_t)(to*32+r)*K + tk*32 + c];
    }
    __syncthreads();
    #pragma unroll
    for(int p=0;p<4;p++){
      int r=r8+p*8;
      out[(size_t)(tk*32+r)*O + to*32 + c]=s[c][r];
    }
  }
}

// -------- fused knn + edge1 + edge2: per bm, all in LDS ---------------------
// 512 threads / 8 waves; ~57 KB LDS -> 2 blocks/CU.
// This round: zs/ds bufs -> [pt][68] with XOR quad swizzle; gathers read
// f32x4 along channels (4x fewer LDS instrs); epilogues store f32x4.
// Max-over-k order and all FP math unchanged -> bit-identical output.
__global__ __launch_bounds__(512) void k_knne12(const float* __restrict__ xyz,
    const float* __restrict__ feats,
    const unsigned short* __restrict__ W1h, const unsigned short* __restrict__ W1l,
    const unsigned short* __restrict__ W2h, const unsigned short* __restrict__ W2l,
    const float* __restrict__ g1, const float* __restrict__ b1,
    const float* __restrict__ g2, const float* __restrict__ b2,
    unsigned short* __restrict__ cat){
  __shared__ __align__(16) float bufA[64*68];   // zs [pt][ch], swizzled quads
  __shared__ __align__(16) float bufB[64*68];   // ds [pt][ch], swizzled quads
  __shared__ __align__(16) unsigned short sb[64*136]; // x split -> e1out split
  __shared__ int   ips[64*16];
  __shared__ float sx0[64], sx1[64], sx2[64], sxx[64];
  int bm = blockIdx.x;
  int tid = threadIdx.x, n = tid&63, s = tid>>6;
  int wid = tid>>6, lane = tid&63;
  int l15 = lane&15, q = lane>>4;
  // ---- issue feats loads early (latency hidden under phase 1) ----
  const float* fb = feats + (size_t)bm*3904;   // 64*61
  float fv[8];
  #pragma unroll
  for(int i=0;i<8;i++){
    int idx = tid + i*512;
    fv[i] = (idx<3904) ? fb[idx] : 0.f;
  }
  if(s==0){
    const float* xp = xyz + (size_t)(bm*64+n)*3;
    float px=xp[0], py=xp[1], pz=xp[2];
    sx0[n]=px; sx1[n]=py; sx2[n]=pz; sxx[n]=px*px+py*py+pz*pz;
  }
  __syncthreads();
  // ---- phase 1: top-16 (8 waves x 8 points; 8 lanes/point x 8 candidates) --
  {
    int p = lane>>3, seg = lane&7;
    int n1 = wid*8 + p;
    float px=sx0[n1], py=sx1[n1], pz=sx2[n1], xxn=sxx[n1];
    float pdr[8];
    #pragma unroll
    for(int t=0;t<8;t++){
      int m = seg*8+t;
      pdr[t] = 2.f*(px*sx0[m]+py*sx1[m]+pz*sx2[m]) - xxn - sxx[m];
    }
    for(int j=0;j<16;j++){
      float bv=-3.4e38f; int bi=seg*8;
      #pragma unroll
      for(int t=0;t<8;t++){ if(pdr[t]>bv){bv=pdr[t]; bi=seg*8+t;} }  // strict >: lowest idx
      float ov; int oi;
      ov=__shfl_xor(bv,1); oi=__shfl_xor(bi,1);
      if(ov>bv || (ov==bv && oi<bi)){bv=ov;bi=oi;}
      ov=__shfl_xor(bv,2); oi=__shfl_xor(bi,2);
      if(ov>bv || (ov==bv && oi<bi)){bv=ov;bi=oi;}
      ov=__shfl_xor(bv,4); oi=__shfl_xor(bi,4);
      if(ov>bv || (ov==bv && oi<bi)){bv=ov;bi=oi;}
      if(seg==0) ips[n1*16+j]=bi;
      if((bi>>3)==seg) pdr[bi&7]=-3.4e38f;
    }
  }
  // ---- phase 2: split x into sb (regs -> LDS; loads already landed) ----
  {
    if(s==0){
      unsigned short* r = sb + n*136;
      float px=sx0[n], py=sx1[n], pz=sx2[n];
      unsigned short h;
      h=f2bs(px); r[0]=h; r[64]=f2bs(px-bs2f(h));
      h=f2bs(py); r[1]=h; r[65]=f2bs(py-bs2f(h));
      h=f2bs(pz); r[2]=h; r[66]=f2bs(pz-bs2f(h));
    }
    #pragma unroll
    for(int i=0;i<8;i++){
      int idx = tid + i*512;
      if(idx<3904){
        float v = fv[i];
        int row = idx/61, cc = idx - row*61;
        unsigned short h=f2bs(v);
        sb[row*136 + 3+cc]      = h;
        sb[row*136 + 64 + 3+cc] = f2bs(v-bs2f(h));
      }
    }
  }
  __syncthreads();
  // ---- phase 3: edge1 MFMA (8 waves x 16 weight-rows) ----
  {
    int rbase = wid*16;
    f32x4 acc[4];
    #pragma unroll
    for(int d=0;d<4;d++) acc[d]=(f32x4){0.f,0.f,0.f,0.f};
    #pragma unroll
    for(int kc=0;kc<2;kc++){
      int k0=kc*32;
      size_t a0=(size_t)(rbase+l15)*64 + k0 + q*8;
      bf16x8 a0h=*(const bf16x8*)(W1h+a0), a0l=*(const bf16x8*)(W1l+a0);
      #pragma unroll
      for(int nt=0;nt<4;nt++){
        int row = nt*16 + l15;
        bf16x8 bh = *(const bf16x8*)&sb[row*136 + k0 + q*8];
        bf16x8 bl = *(const bf16x8*)&sb[row*136 + 64 + k0 + q*8];
        acc[nt]=MF(a0h,bh,acc[nt]);
        acc[nt]=MF(a0h,bl,acc[nt]);
        acc[nt]=MF(a0l,bh,acc[nt]);
      }
    }
    __syncthreads();
    float* dst = (wid<4)? bufA : bufB;
    int ro4 = (wid&3)*4;   // channel-quad base: channels (wid&3)*16 + q*4 + rr
    #pragma unroll
    for(int nt=0;nt<4;nt++)
      *(f32x4*)&dst[bidx(nt*16+l15, ro4+q)] = acc[nt];
  }
  __syncthreads();
  // ---- phase 4: gather edge1 (f32x4 along ch); write cats + sb ----
  {
    #pragma unroll
    for(int it=0; it<2; ++it){
      int item = tid + it*512;
      int nn = item>>4, c4 = item&15, o0 = c4*4;
      const int* ip = &ips[nn*16];
      f32x4 mz = {-3.4e38f,-3.4e38f,-3.4e38f,-3.4e38f};
      #pragma unroll
      for(int k=0;k<16;k++){
        f32x4 z = *(const f32x4*)&bufA[bidx(ip[k], c4)];
        mz[0]=fmaxf(mz[0],z[0]); mz[1]=fmaxf(mz[1],z[1]);
        mz[2]=fmaxf(mz[2],z[2]); mz[3]=fmaxf(mz[3],z[3]);
      }
      f32x4 d = *(const f32x4*)&bufB[bidx(nn, c4)];
      float4 sg = *(const float4*)&g1[o0];
      float4 bb = *(const float4*)&b1[o0];
      float v[4];
      v[0]=fmaxf(sg.x*BNS*(mz[0]+d[0])+bb.x,0.f);
      v[1]=fmaxf(sg.y*BNS*(mz[1]+d[1])+bb.y,0.f);
      v[2]=fmaxf(sg.z*BNS*(mz[2]+d[2])+bb.z,0.f);
      v[3]=fmaxf(sg.w*BNS*(mz[3]+d[3])+bb.w,0.f);
      unsigned short hv[4], lv[4];
      #pragma unroll
      for(int c=0;c<4;c++){ hv[c]=f2bs(v[c]); lv[c]=f2bs(v[c]-bs2f(hv[c])); }
      ushort4 hq=make_ushort4(hv[0],hv[1],hv[2],hv[3]);
      ushort4 lq=make_ushort4(lv[0],lv[1],lv[2],lv[3]);
      size_t cb = ((size_t)bm*64+nn)*384 + o0;
      *(ushort4*)&cat[cb] = hq; *(ushort4*)&cat[cb+192] = lq;
      *(ushort4*)&sb[nn*136 + o0] = hq;        // x dead after phase 3
      *(ushort4*)&sb[nn*136 + 64 + o0] = lq;
    }
  }
  // ---- phase 5: edge2 (2 chunks of 64 o) from sb ----
  for(int ch=0; ch<2; ch++){
    __syncthreads();
    int wrow = ((wid<4)?0:128) + ch*64 + (wid&3)*16;
    f32x4 acc[4];
    #pragma unroll
    for(int d=0;d<4;d++) acc[d]=(f32x4){0.f,0.f,0.f,0.f};
    #pragma unroll
    for(int kc=0;kc<2;kc++){
      int k0=kc*32;
      size_t a0=(size_t)(wrow+l15)*64 + k0 + q*8;
      bf16x8 a0h=*(const bf16x8*)(W2h+a0), a0l=*(const bf16x8*)(W2l+a0);
      #pragma unroll
      for(int nt=0;nt<4;nt++){
        int row = nt*16 + l15;
        bf16x8 bh = *(const bf16x8*)&sb[row*136 + k0 + q*8];
        bf16x8 bl = *(const bf16x8*)&sb[row*136 + 64 + k0 + q*8];
        acc[nt]=MF(a0h,bh,acc[nt]);
        acc[nt]=MF(a0h,bl,acc[nt]);
        acc[nt]=MF(a0l,bh,acc[nt]);
      }
    }
    __syncthreads();
    float* dst = (wid<4)? bufA : bufB;
    int ro4 = (wid&3)*4;
    #pragma unroll
    for(int nt=0;nt<4;nt++)
      *(f32x4*)&dst[bidx(nt*16+l15, ro4+q)] = acc[nt];
    __syncthreads();
    #pragma unroll
    for(int it=0; it<2; ++it){
      int item = tid + it*512;
      int nn = item>>4, c4 = item&15, o0 = c4*4;
      const int* ip = &ips[nn*16];
      f32x4 mz = {-3.4e38f,-3.4e38f,-3.4e38f,-3.4e38f};
      #pragma unroll
      for(int k=0;k<16;k++){
        f32x4 z = *(const f32x4*)&bufA[bidx(ip[k], c4)];
        mz[0]=fmaxf(mz[0],z[0]); mz[1]=fmaxf(mz[1],z[1]);
        mz[2]=fmaxf(mz[2],z[2]); mz[3]=fmaxf(mz[3],z[3]);
      }
      f32x4 d = *(const f32x4*)&bufB[bidx(nn, c4)];
      float4 sg = *(const float4*)&g2[ch*64+o0];
      float4 bb = *(const float4*)&b2[ch*64+o0];
      float v[4];
      v[0]=fmaxf(sg.x*BNS*(mz[0]+d[0])+bb.x,0.f);
      v[1]=fmaxf(sg.y*BNS*(mz[1]+d[1])+bb.y,0.f);
      v[2]=fmaxf(sg.z*BNS*(mz[2]+d[2])+bb.z,0.f);
      v[3]=fmaxf(sg.w*BNS*(mz[3]+d[3])+bb.w,0.f);
      unsigned short hv[4], lv[4];
      #pragma unroll
      for(int c=0;c<4;c++){ hv[c]=f2bs(v[c]); lv[c]=f2bs(v[c]-bs2f(hv[c])); }
      size_t cb = ((size_t)bm*64+nn)*384 + 64 + ch*64 + o0;
      *(ushort4*)&cat[cb]     = make_ushort4(hv[0],hv[1],hv[2],hv[3]);
      *(ushort4*)&cat[cb+192] = make_ushort4(lv[0],lv[1],lv[2],lv[3]);
    }
  }
}

// ------- fused MLP: cal1 -> cal2 -> gate -> exp1 -> exp2 -> pool ------------
// One block per bm group (64 rows), 512 threads. LDS overlay = 80 KB
// (2 blocks/CU). Round-11 build (setprio removed; proven 73.5 us).
__global__ __launch_bounds__(512,4) void k_mlp(
    const unsigned short* __restrict__ Whi, const unsigned short* __restrict__ Wlo,
    const unsigned short* __restrict__ cats,
    const float* __restrict__ c1g, const float* __restrict__ c1b,
    const float* __restrict__ c2bias,
    const float* __restrict__ e1g, const float* __restrict__ e1b,
    const float* __restrict__ e2g, const float* __restrict__ e2b,
    float* __restrict__ pool){
  __shared__ __align__(16) unsigned short buf[8*4096];
  __shared__ __align__(16) unsigned short calB[2*4096];
  int bm = blockIdx.x;
  int tid = threadIdx.x, wid = tid>>6, lane = tid&63;
  int l15 = lane&15, q = lane>>4;

  // ---- issue cal1 kc=0 weight loads before staging (hide behind barrier) --
  const unsigned short* w1h = Whi + 24576;
  const unsigned short* w1l = Wlo + 24576;
  int c1ot = wid>>1, c1rh = wid&1;
  size_t c1wo0 = (size_t)(c1ot*16+l15)*192 + q*8;
  bf16x8 cah = *(const bf16x8*)(w1h+c1wo0);
  bf16x8 cal_ = *(const bf16x8*)(w1l+c1wo0);

  // ---- stage X (split, chunked+swizzled) into buf[0..5] ----
  size_t xb = (size_t)bm*24576;  // 64*384
  #pragma unroll
  for(int i=0;i<6;i++){
    int U = tid + i*512;
    int kc = U>>9, w = U&511, rr = w>>3, up = w&7, u = up ^ (rr&7);
    const unsigned short* src = cats + xb + (size_t)rr*384
      + (u<4 ? (kc*32 + u*8) : (192 + kc*32 + (u-4)*8));
    *(uint4*)&buf[kc*4096 + w*8] = *(const uint4*)src;
  }
  __syncthreads();

  // ---- cal1: out 64, K=192 -> calB; weight rotation ----
  f32x4 a0={0.f,0.f,0.f,0.f}, a1={0.f,0.f,0.f,0.f};
  {
    int r0 = c1rh*32+l15, r1 = c1rh*32+16+l15;
    #pragma unroll
    for(int kc=0;kc<6;kc++){
      bf16x8 nah, nal;
      if(kc<5){
        size_t wo = c1wo0 + (kc+1)*32;
        nah=*(const bf16x8*)(w1h+wo); nal=*(const bf16x8*)(w1l+wo);
      }
      const unsigned short* cb = buf + kc*4096;
      bf16x8 xh0=*(const bf16x8*)&cb[(r0*8+((  q)^(r0&7)))*8];
      bf16x8 xl0=*(const bf16x8*)&cb[(r0*8+((4+q)^(r0&7)))*8];
      bf16x8 xh1=*(const bf16x8*)&cb[(r1*8+((  q)^(r1&7)))*8];
      bf16x8 xl1=*(const bf16x8*)&cb[(r1*8+((4+q)^(r1&7)))*8];
      a0=MF(cah,xh0,a0); a1=MF(cah,xh1,a1);
      a0=MF(cah,xl0,a0); a1=MF(cah,xl1,a1);
      a0=MF(cal_,xh0,a0); a1=MF(cal_,xh1,a1);
      cah=nah; cal_=nal;
    }
  }
  // ---- prefetch cal2 kc=0 weights (overlaps cal1 epilogue + barrier) ----
  const unsigned short* w2h = Whi + 36864;
  const unsigned short* w2l = Wlo + 36864;
  bf16x8 c2h[6], c2l[6];
  #pragma unroll
  for(int i=0;i<6;i++){
    int ot = (wid*6+i)>>2;
    size_t wo=(size_t)(ot*16+l15)*64 + q*8;
    c2h[i]=*(const bf16x8*)(w2h+wo); c2l[i]=*(const bf16x8*)(w2l+wo);
  }
  // ---- cal1 epilogue (vectorized) ----
  {
    int c0 = c1ot*16+q*4;
    float4 sg = *(const float4*)&c1g[c0];
    float4 bb = *(const float4*)&c1b[c0];
    float v0[4], v1[4];
    v0[0]=fmaxf(a0[0]*sg.x*BNS+bb.x,0.f); v1[0]=fmaxf(a1[0]*sg.x*BNS+bb.x,0.f);
    v0[1]=fmaxf(a0[1]*sg.y*BNS+bb.y,0.f); v1[1]=fmaxf(a1[1]*sg.y*BNS+bb.y,0.f);
    v0[2]=fmaxf(a0[2]*sg.z*BNS+bb.z,0.f); v1[2]=fmaxf(a1[2]*sg.z*BNS+bb.z,0.f);
    v0[3]=fmaxf(a0[3]*sg.w*BNS+bb.w,0.f); v1[3]=fmaxf(a1[3]*sg.w*BNS+bb.w,0.f);
    put_split4(calB, c1rh*32+l15,    c0, v0);
    put_split4(calB, c1rh*32+16+l15, c0, v1);
  }
  __syncthreads();
  // ---- cal2: out 192, K=64 (calB); then sigmoid gate -> buf in place ----
  f32x4 ac[6];
  #pragma unroll
  for(int i=0;i<6;i++) ac[i]=(f32x4){0.f,0.f,0.f,0.f};
  #pragma unroll
  for(int kc=0;kc<2;kc++){
    const unsigned short* cb = calB + kc*4096;
    if(kc==1){
      #pragma unroll
      for(int i=0;i<6;i++){
        int ot = (wid*6+i)>>2;
        size_t wo=(size_t)(ot*16+l15)*64 + 32 + q*8;
        c2h[i]=*(const bf16x8*)(w2h+wo); c2l[i]=*(const bf16x8*)(w2l+wo);
      }
    }
    #pragma unroll
    for(int i=0;i<6;i++){
      int nf=(wid*6+i)&3;
      int r=nf*16+l15;
      bf16x8 xh=*(const bf16x8*)&cb[(r*8+((  q)^(r&7)))*8];
      bf16x8 xl=*(const bf16x8*)&cb[(r*8+((4+q)^(r&7)))*8];
      ac[i]=MF(c2h[i],xh,ac[i]); ac[i]=MF(c2h[i],xl,ac[i]); ac[i]=MF(c2l[i],xh,ac[i]);
    }
  }
  // ---- prefetch exp1 kc=0 weights (overlaps gate) ----
  const unsigned short* e1wh=Whi+49152; const unsigned short* e1wl=Wlo+49152;
  int ob1 = wid*32;
  bf16x8 p1h[2], p1l[2];
  #pragma unroll
  for(int mt=0;mt<2;mt++){
    size_t wo=(size_t)(ob1+mt*16+l15)*192 + q*8;
    p1h[mt]=*(const bf16x8*)(e1wh+wo); p1l[mt]=*(const bf16x8*)(e1wl+wo);
  }
  // ---- gate (vectorized RMW) ----
  #pragma unroll
  for(int i=0;i<6;i++){
    int j=wid*6+i, ot=j>>2, nf=j&3, n=nf*16+l15;
    int c0=ot*16+q*4;
    float4 cb4 = *(const float4*)&c2bias[c0];
    float xv[4];
    get_split4(buf, n, c0, xv);
    xv[0] *= 1.f/(1.f+__expf(-(ac[i][0]+cb4.x)));
    xv[1] *= 1.f/(1.f+__expf(-(ac[i][1]+cb4.y)));
    xv[2] *= 1.f/(1.f+__expf(-(ac[i][2]+cb4.z)));
    xv[3] *= 1.f/(1.f+__expf(-(ac[i][3]+cb4.w)));
    put_split4(buf, n, c0, xv);
  }
  __syncthreads();
  // ---- exp1: out 256, K=192; regs accumulate, then overwrite buf ----
  {
    f32x4 e1a[2][4];
    #pragma unroll
    for(int a=0;a<2;a++)
      #pragma unroll
      for(int d=0;d<4;d++) e1a[a][d]=(f32x4){0.f,0.f,0.f,0.f};
    #pragma unroll
    for(int kc=0;kc<6;kc++){
      bf16x8 nh[2], nl[2];
      if(kc<5){
        #pragma unroll
        for(int mt=0;mt<2;mt++){
          size_t wo=(size_t)(ob1+mt*16+l15)*192 + (kc+1)*32 + q*8;
          nh[mt]=*(const bf16x8*)(e1wh+wo); nl[mt]=*(const bf16x8*)(e1wl+wo);
        }
      }
      const unsigned short* cb = buf + kc*4096;
      #pragma unroll
      for(int nf=0;nf<4;nf++){
        int r=nf*16+l15;
        bf16x8 xh=*(const bf16x8*)&cb[(r*8+((  q)^(r&7)))*8];
        bf16x8 xl=*(const bf16x8*)&cb[(r*8+((4+q)^(r&7)))*8];
        e1a[0][nf]=MF(p1h[0],xh,e1a[0][nf]); e1a[1][nf]=MF(p1h[1],xh,e1a[1][nf]);
        e1a[0][nf]=MF(p1h[0],xl,e1a[0][nf]); e1a[1][nf]=MF(p1h[1],xl,e1a[1][nf]);
        e1a[0][nf]=MF(p1l[0],xh,e1a[0][nf]); e1a[1][nf]=MF(p1l[1],xh,e1a[1][nf]);
      }
      p1h[0]=nh[0]; p1h[1]=nh[1]; p1l[0]=nl[0]; p1l[1]=nl[1];
    }
    __syncthreads();   // all reads of X retired; buf is now free
    // prefetch exp2 kc=0 weights (overlaps exp1 epilogue + barrier)
    const unsigned short* e2wh=Whi+98304; const unsigned short* e2wl=Wlo+98304;
    int ob2 = wid*64;
    bf16x8 p2h[4], p2l[4];
    #pragma unroll
    for(int mt=0;mt<4;mt++){
      size_t wo=(size_t)(ob2+mt*16+l15)*256 + q*8;
      p2h[mt]=*(const bf16x8*)(e2wh+wo); p2l[mt]=*(const bf16x8*)(e2wl+wo);
    }
    // exp1 epilogue (vectorized)
    #pragma unroll
    for(int mt=0;mt<2;mt++){
      int c0 = ob1+mt*16+q*4;
      float4 sg = *(const float4*)&e1g[c0];
      float4 bb = *(const float4*)&e1b[c0];
      #pragma unroll
      for(int nf=0;nf<4;nf++){
        float v[4];
        v[0]=fmaxf(e1a[mt][nf][0]*sg.x*BNS+bb.x,0.f);
        v[1]=fmaxf(e1a[mt][nf][1]*sg.y*BNS+bb.y,0.f);
        v[2]=fmaxf(e1a[mt][nf][2]*sg.z*BNS+bb.z,0.f);
        v[3]=fmaxf(e1a[mt][nf][3]*sg.w*BNS+bb.w,0.f);
        put_split4(buf, nf*16+l15, c0, v);
      }
    }
    __syncthreads();
    // ---- exp2: out 512, K=256; bn -> max-pool over 64 rows ----
    f32x4 a2[4][4];
    #pragma unroll
    for(int a=0;a<4;a++)
      #pragma unroll
      for(int d=0;d<4;d++) a2[a][d]=(f32x4){0.f,0.f,0.f,0.f};
    {  // kc = 0 (prefetched weights)
      const unsigned short* cb = buf;
      #pragma unroll
      for(int nf=0;nf<4;nf++){
        int r=nf*16+l15;
        bf16x8 xh=*(const bf16x8*)&cb[(r*8+((  q)^(r&7)))*8];
        bf16x8 xl=*(const bf16x8*)&cb[(r*8+((4+q)^(r&7)))*8];
        #pragma unroll
        for(int mt=0;mt<4;mt++) a2[mt][nf]=MF(p2h[mt],xh,a2[mt][nf]);
        #pragma unroll
        for(int mt=0;mt<4;mt++) a2[mt][nf]=MF(p2h[mt],xl,a2[mt][nf]);
        #pragma unroll
        for(int mt=0;mt<4;mt++) a2[mt][nf]=MF(p2l[mt],xh,a2[mt][nf]);
      }
    }
    for(int kc=1;kc<8;kc++){
      bf16x8 ch[4], cl[4];
      #pragma unroll
      for(int mt=0;mt<4;mt++){
        size_t wo=(size_t)(ob2+mt*16+l15)*256 + kc*32 + q*8;
        ch[mt]=*(const bf16x8*)(e2wh+wo); cl[mt]=*(const bf16x8*)(e2wl+wo);
      }
      const unsigned short* cb = buf + kc*4096;
      #pragma unroll
      for(int nf=0;nf<4;nf++){
        int r=nf*16+l15;
        bf16x8 xh=*(const bf16x8*)&cb[(r*8+((  q)^(r&7)))*8];
        bf16x8 xl=*(const bf16x8*)&cb[(r*8+((4+q)^(r&7)))*8];
        #pragma unroll
        for(int mt=0;mt<4;mt++) a2[mt][nf]=MF(ch[mt],xh,a2[mt][nf]);
        #pragma unroll
        for(int mt=0;mt<4;mt++) a2[mt][nf]=MF(ch[mt],xl,a2[mt][nf]);
      }
      #pragma unroll
      for(int nf=0;nf<4;nf++){
        int r=nf*16+l15;
        bf16x8 xh=*(const bf16x8*)&cb[(r*8+((  q)^(r&7)))*8];
        #pragma unroll
        for(int mt=0;mt<4;mt++) a2[mt][nf]=MF(cl[mt],xh,a2[mt][nf]);
      }
    }
    int b = bm>>8, m = bm&255;
    #pragma unroll
    for(int mt=0;mt<4;mt++){
      int c0 = ob2+mt*16+q*4;
      float4 sg = *(const float4*)&e2g[c0];
      float4 bb = *(const float4*)&e2b[c0];
      float s[4]={sg.x*BNS,sg.y*BNS,sg.z*BNS,sg.w*BNS};
      float bbv[4]={bb.x,bb.y,bb.z,bb.w};
      #pragma unroll
      for(int rr=0;rr<4;rr++){
        float v = a2[mt][0][rr]*s[rr]+bbv[rr];
        v = fmaxf(v, a2[mt][1][rr]*s[rr]+bbv[rr]);
        v = fmaxf(v, a2[mt][2][rr]*s[rr]+bbv[rr]);
        v = fmaxf(v, a2[mt][3][rr]*s[rr]+bbv[rr]);
        v = fmaxf(v, 0.f);
        v = fmaxf(v, __shfl_xor(v,1));
        v = fmaxf(v, __shfl_xor(v,2));
        v = fmaxf(v, __shfl_xor(v,4));
        v = fmaxf(v, __shfl_xor(v,8));
        if(l15==0) pool[((size_t)b*512 + c0+rr)*256 + m] = v;
      }
    }
  }
}

// ------- fused head: red -> sc1 -> sc2, one block = (b, 2 cols) -------------
// 1024 threads: K-dim split across 4 quarters (h), LDS partial combine.
__global__ __launch_bounds__(1024) void k_headf(const float* __restrict__ Wt_red,
    const float* __restrict__ Wt_s1, const float* __restrict__ Wt_s2,
    const float* __restrict__ pool, float* __restrict__ Og,
    const float* __restrict__ red_g, const float* __restrict__ red_b,
    const float* __restrict__ n1g, const float* __restrict__ n1b,
    const float* __restrict__ s1b, const float* __restrict__ s2b,
    const float* __restrict__ n2g, const float* __restrict__ n2b){
  __shared__ float P[512*3];
  __shared__ float X1[256*3];
  __shared__ float H[256*3];
  __shared__ float PB[256*9];
  int g = blockIdx.x;
  int b = g>>7, mg = g&127;
  int m0 = mg*2;
  int tid = threadIdx.x;
  int o = tid&255, h = tid>>8;   // h in 0..3
  if(tid<512){
    int c = tid;
    float2 v = *(const float2*)&pool[((size_t)b*512+c)*256 + m0];
    P[c*3+0]=v.x; P[c*3+1]=v.y;
  }
  __syncthreads();
  float a0=0.f, a1=0.f;
  // red: K=512, quarter per h
  {
    int c0 = h*128;
    #pragma unroll 8
    for(int i=0;i<128;i++){
      int c = c0+i;
      float w = Wt_red[c*256+o];
      a0 += w*P[c*3]; a1 += w*P[c*3+1];
    }
  }
  PB[o*9+h*2]=a0; PB[o*9+h*2+1]=a1;
  __syncthreads();
  a0 = (PB[o*9+0]+PB[o*9+2])+(PB[o*9+4]+PB[o*9+6]);
  a1 = (PB[o*9+1]+PB[o*9+3])+(PB[o*9+5]+PB[o*9+7]);
  float x0r,x1r;
  {
    float s=red_g[o]*BNS, bi=red_b[o], s1=n1g[o]*BNS, b1=n1b[o];
    float r0=fmaxf(a0*s+bi,0.f), r1=fmaxf(a1*s+bi,0.f);
    x0r=2.f*r0*s1+b1; x1r=2.f*r1*s1+b1;
    if(h==0){ X1[o*3]=x0r; X1[o*3+1]=x1r; }
  }
  __syncthreads();
  // sc1: K=256, quarters of 64
  a0=0.f; a1=0.f;
  {
    int c0 = h*64;
    #pragma unroll 8
    for(int i=0;i<64;i++){
      int c = c0+i;
      float w = Wt_s1[c*256+o];
      a0 += w*X1[c*3]; a1 += w*X1[c*3+1];
    }
  }
  PB[o*9+h*2]=a0; PB[o*9+h*2+1]=a1;
  __syncthreads();
  a0 = (PB[o*9+0]+PB[o*9+2])+(PB[o*9+4]+PB[o*9+6]);
  a1 = (PB[o*9+1]+PB[o*9+3])+(PB[o*9+5]+PB[o*9+7]);
  {
    float bi=s1b[o];
    if(h==0){ H[o*3]=fmaxf(a0+bi,0.f); H[o*3+1]=fmaxf(a1+bi,0.f); }
  }
  __syncthreads();
  // sc2 + residual + bn2
  a0=0.f; a1=0.f;
  {
    int c0 = h*64;
    #pragma unroll 8
    for(int i=0;i<64;i++){
      int c = c0+i;
      float w = Wt_s2[c*256+o];
      a0 += w*H[c*3]; a1 += w*H[c*3+1];
    }
  }
  PB[o*9+h*2]=a0; PB[o*9+h*2+1]=a1;
  __syncthreads();
  if(h==0){
    a0 = (PB[o*9+0]+PB[o*9+2])+(PB[o*9+4]+PB[o*9+6]);
    a1 = (PB[o*9+1]+PB[o*9+3])+(PB[o*9+5]+PB[o*9+7]);
    float bi=s2b[o], s2=n2g[o]*BNS, b2=n2b[o];
    float v0=(x0r+a0+bi)*s2+b2, v1=(x1r+a1+bi)*s2+b2;
    *(float2*)&Og[((size_t)b*256+o)*256 + m0] = make_float2(v0,v1);
  }
}

extern "C" void kernel_launch(void* const* d_in, const int* in_sizes, int n_in,
                              void* d_out, int out_size, void* d_ws, size_t ws_size,
                              hipStream_t stream){
  const float* xyz     =(const float*)d_in[0];
  const float* feats   =(const float*)d_in[1];
  const float* e1_w    =(const float*)d_in[2];
  const float* e1_g    =(const float*)d_in[3];
  const float* e1_b    =(const float*)d_in[4];
  const float* e2_w    =(const float*)d_in[5];
  const float* e2_g    =(const float*)d_in[6];
  const float* e2_b    =(const float*)d_in[7];
  const float* cal1_w  =(const float*)d_in[8];
  const float* cal1_g  =(const float*)d_in[9];
  const float* cal1_b  =(const float*)d_in[10];
  const float* cal2_w  =(const float*)d_in[11];
  const float* cal2_bias=(const float*)d_in[12];
  const float* exp1_w  =(const float*)d_in[13];
  const float* exp1_g  =(const float*)d_in[14];
  const float* exp1_b  =(const float*)d_in[15];
  const float* exp2_w  =(const float*)d_in[16];
  const float* exp2_g  =(const float*)d_in[17];
  const float* exp2_b  =(const float*)d_in[18];
  const float* red_w   =(const float*)d_in[19];
  const float* red_g   =(const float*)d_in[20];
  const float* red_b   =(const float*)d_in[21];
  const float* sc1_w   =(const float*)d_in[22];
  const float* sc1_b   =(const float*)d_in[23];
  const float* sc2_w   =(const float*)d_in[24];
  const float* sc2_b   =(const float*)d_in[25];
  const float* sc_n1_g =(const float*)d_in[26];
  const float* sc_n1_b =(const float*)d_in[27];
  const float* sc_n2_g =(const float*)d_in[28];
  const float* sc_n2_b =(const float*)d_in[29];

  char* wsb=(char*)d_ws;
  unsigned short* cats=(unsigned short*)(wsb + 10485760);         // 24 MB [row][2][192]
  float*          pool=(float*)         (wsb + 69206016);         // 1 MB
  unsigned short* Whi =(unsigned short*)(wsb + 75497472);         // 448 KB
  unsigned short* Wlo =(unsigned short*)(wsb + 76021760);         // 448 KB
  float*          Wt_red=(float*)       (wsb + 76546048);         // 512 KB
  float*          Wt_s1 =(float*)       (wsb + 77070336);         // 256 KB
  float*          Wt_s2 =(float*)       (wsb + 77332480);         // 256 KB
  unsigned short* e1e_h=Whi;          unsigned short* e1e_l=Wlo;          // 128x64
  unsigned short* e2e_h=Whi+8192;     unsigned short* e2e_l=Wlo+8192;     // 256x64

  k_prep      <<<552,256,0,stream>>>(e1_w,e2_w,cal1_w,cal2_w,exp1_w,exp2_w,Whi,Wlo,
                                     red_w,sc1_w,sc2_w,Wt_red,Wt_s1,Wt_s2);
  k_knne12    <<<512,512,0,stream>>>(xyz,feats,e1e_h,e1e_l,e2e_h,e2e_l,
                                     e1_g,e1_b,e2_g,e2_b,cats);
  k_mlp       <<<512,512,0,stream>>>(Whi,Wlo,cats,cal1_g,cal1_b,cal2_bias,
                                     exp1_g,exp1_b,exp2_g,exp2_b,pool);
  k_headf     <<<256,1024,0,stream>>>(Wt_red,Wt_s1,Wt_s2,pool,(float*)d_out,
                                      red_g,red_b,sc_n1_g,sc_n1_b,sc1_b,sc2_b,sc_n2_g,sc_n2_b);
}